// Round 18
// baseline (464.589 us; speedup 1.0000x reference)
//
#include <hip/hip_runtime.h>
#include <math.h>

// Decoder_9887014716020 — R17: k_off ILP-8 channel blocking (24 loads in
// flight; was a VGPR=12 serial scalar-load chain at 29% VALUBusy).
// Rest identical to R16 (bf16 NHWC mirrors, 1-wave k_dcn, ILP-8 k_gemm1).
// B=2, H=W=64 (HW=4096), HD=40, N_NODES=6, 10 edges.

#define HWSH 12      // 4096 = 1<<12

__device__ __constant__ int c_src[10] = {0,1,1,1,2,2,3,4,4,5};
__device__ __constant__ int c_dst[10] = {1,0,2,4,1,3,2,1,5,4};

typedef __attribute__((ext_vector_type(8))) short short8;
typedef __attribute__((ext_vector_type(4))) float f32x4;
typedef __attribute__((ext_vector_type(4))) unsigned int uint4v;

// ---- workspace layout (float offsets; NODESN/H1N reinterpreted as ushort) --
constexpr size_t NODES_OFF  = 0;          // NCHW 2*240*4096 fp32
constexpr size_t NODESN_OFF = 1966080;    // NHWC [b][4096][240] BF16 (ushort)
constexpr size_t BG_OFF     = 3932160;    // 2*40*4096
constexpr size_t H1_OFF     = 4259840;    // NCHW 20*80*4096 fp32
constexpr size_t H1N_OFF    = 10813440;   // NHWC [20][4096][80] BF16 (ushort)
constexpr size_t OM_OFF     = 17367040;   // 10*2*27*4096
constexpr size_t MSGS_OFF   = 19578880;   // NHWC [6*2][4096][40] fp32
constexpr size_t NEWBN_OFF  = 21544960;   // NCHW 2*240*4096
constexpr size_t BS1_OFF    = 23511040;   // bf16 B-frags s1: 691200 ushort
constexpr size_t BS2_OFF    = 23856640;   // s2: 414720 ushort
constexpr size_t WO1T_OFF   = 24064000;   // 10*80*9*27
constexpr size_t WO2T_OFF   = 24258400;
constexpr size_t PWT_OFF    = 24452800;   // 256*240
constexpr size_t BGWT_OFF   = 24514240;   // 768*40
constexpr size_t UW1T_OFF   = 24544960;   // 6*80*32
constexpr size_t UW2T_OFF   = 24560320;   // 6*32*40  -> end 24,568,000 (98.3MB)

__device__ inline float relu_(float x){ return x > 0.f ? x : 0.f; }
__device__ inline float sigm_(float x){ return 1.f/(1.f + __expf(-x)); }
__device__ inline unsigned short bf16rne(float x){
  unsigned int u = __float_as_uint(x);
  unsigned int r = (u + 0x7fffu + ((u>>16)&1u)) >> 16;
  return (unsigned short)r;
}
__device__ inline float bf16f(unsigned short h){
  return __uint_as_float(((unsigned int)h)<<16);
}
__device__ inline float bf16lo(unsigned int u){ return __uint_as_float(u<<16); }
__device__ inline float bf16hi(unsigned int u){ return __uint_as_float(u & 0xffff0000u); }

// ======== k_pre: weight transposes + bf16 B-fragment prepack (2510 blocks) ==
__global__ __launch_bounds__(256) void k_pre(
    const float* __restrict__ off1w, const float* __restrict__ off2w,
    const float* __restrict__ p_w,  const float* __restrict__ bg_w,
    const float* __restrict__ u_w1, const float* __restrict__ u_w2,
    const float* __restrict__ dcn1w, const float* __restrict__ dcn2w,
    float* __restrict__ ws)
{
  const int bid = blockIdx.x;
  const int tid = threadIdx.x;
  if (bid < 1969){
    int i = bid*256 + tid;
    if (i < 194400){                       // wo1t[e][c][ktap][oc]
      int oc=i%27; int t=i/27; int kk=t%9; t/=9; int c=t%80; int e=t/80;
      ws[WO1T_OFF+i] = off1w[(size_t)((e*27+oc)*80+c)*9+kk];
    } else if (i < 388800){
      int j = i-194400;
      int oc=j%27; int t=j/27; int kk=t%9; t/=9; int c=t%80; int e=t/80;
      ws[WO2T_OFF+j] = off2w[(size_t)((e*27+oc)*80+c)*9+kk];
    } else if (i < 450240){                // pwt[c][o]
      int j = i-388800;
      int o=j%240; int c=j/240;
      ws[PWT_OFF+j] = p_w[(size_t)o*256+c];
    } else if (i < 480960){                // bgwt[c][o]
      int j = i-450240;
      int o=j%40; int c=j/40;
      ws[BGWT_OFF+j] = bg_w[(size_t)o*768+c];
    } else if (i < 496320){                // uw1t[n][c][o]
      int j = i-480960;
      int o=j%32; int t=j/32; int c=t%80; int n=t/80;
      ws[UW1T_OFF+j] = u_w1[(size_t)((n*32+o)*80)+c];
    } else if (i < 504000){                // uw2t[n][c][o]
      int j = i-496320;
      int o=j%40; int t=j/40; int c=t%32; int n=t/32;
      ws[UW2T_OFF+j] = u_w2[(size_t)((n*40+o)*32)+c];
    }
  } else if (bid < 2307){
    // bs1: q = ((e*9+k)*3+kst)*5+nt, per lane 8 bf16
    int t = (bid-1969)*256 + tid;
    if (t < 86400){
      int lane = t & 63; int q = t >> 6;
      int nt = q % 5; int q2 = q/5; int kst = q2 % 3; q2/=3; int k = q2 % 9; int e = q2/9;
      int n  = nt*16 + (lane & 15);
      int c0 = kst*32 + (lane>>4)*8;
      union { unsigned int u[4]; } r;
      unsigned short v[8];
      #pragma unroll
      for (int j=0;j<8;j++){
        int c = c0 + j;
        float w = (c < 80) ? dcn1w[(size_t)((e*80+n)*80+c)*9+k] : 0.f;
        v[j] = bf16rne(w);
      }
      #pragma unroll
      for (int j=0;j<4;j++) r.u[j] = (unsigned int)v[2*j] | ((unsigned int)v[2*j+1]<<16);
      unsigned int* dst = (unsigned int*)((unsigned short*)(ws + BS1_OFF) + (size_t)t*8);
      dst[0]=r.u[0]; dst[1]=r.u[1]; dst[2]=r.u[2]; dst[3]=r.u[3];
    }
  } else {
    // bs2: q = ((e*9+k)*3+kst)*3+nt
    int t = (bid-2307)*256 + tid;
    if (t < 51840){
      int lane = t & 63; int q = t >> 6;
      int nt = q % 3; int q2 = q/3; int kst = q2 % 3; q2/=3; int k = q2 % 9; int e = q2/9;
      int n  = nt*16 + (lane & 15);
      int c0 = kst*32 + (lane>>4)*8;
      union { unsigned int u[4]; } r;
      unsigned short v[8];
      #pragma unroll
      for (int j=0;j<8;j++){
        int c = c0 + j;
        float w = (n < 40 && c < 80) ? dcn2w[(size_t)((e*40+n)*80+c)*9+k] : 0.f;
        v[j] = bf16rne(w);
      }
      #pragma unroll
      for (int j=0;j<4;j++) r.u[j] = (unsigned int)v[2*j] | ((unsigned int)v[2*j+1]<<16);
      unsigned int* dst = (unsigned int*)((unsigned short*)(ws + BS2_OFF) + (size_t)t*8);
      dst[0]=r.u[0]; dst[1]=r.u[1]; dst[2]=r.u[2]; dst[3]=r.u[3];
    }
  }
}

// ======== k_gemm1 v4: ILP-8 blocked loads; NHWC mirror stored bf16 =========
__global__ __launch_bounds__(64, 4) void k_gemm1(
    const float* __restrict__ xp, const float* __restrict__ xh, const float* __restrict__ xf,
    const float* __restrict__ pwt, const float* __restrict__ pg, const float* __restrict__ pb_,
    const float* __restrict__ bgwt, const float* __restrict__ gg, const float* __restrict__ gb,
    float* __restrict__ nodes, unsigned short* __restrict__ nodesn, float* __restrict__ bg)
{
  const int lane = threadIdx.x;
  if (blockIdx.x < 1536){
    const int chunk = blockIdx.x & 31;     // 32 chunks of 256 px (2 batches)
    const int og    = blockIdx.x >> 5;     // 48 groups of 5 oc
    const int b   = chunk >> 4;
    const int px  = ((chunk & 15) << 8) + (lane << 2);
    const int o0  = og*5;
    float acc[4][5];
    #pragma unroll
    for (int p=0;p<4;p++)
      #pragma unroll
      for (int j=0;j<5;j++) acc[p][j]=0.f;
    const float* xb = xp + (((size_t)b)<<20) + px;
    #pragma unroll 1
    for (int c8=0;c8<32;c8++){
      float xv[8][4];
      #pragma unroll
      for (int j=0;j<8;j++)
        *(float4*)&xv[j][0] = *(const float4*)(xb + (((size_t)(c8*8+j))<<HWSH));
      #pragma unroll
      for (int j=0;j<8;j++){
        const float* wr = pwt + (c8*8+j)*240 + o0;
        #pragma unroll
        for (int jj=0;jj<5;jj++){
          float w = wr[jj];
          #pragma unroll
          for (int p=0;p<4;p++) acc[p][jj] = fmaf(xv[j][p], w, acc[p][jj]);
        }
      }
    }
    #pragma unroll
    for (int j=0;j<5;j++){
      int o = o0+j;
      float g = pg[o], bb = pb_[o];
      float v[4];
      #pragma unroll
      for (int p=0;p<4;p++) v[p] = relu_(g*acc[p][j]+bb);
      *(float4*)&nodes[(((size_t)(b*240+o))<<HWSH) + px] = *(float4*)v;
      #pragma unroll
      for (int p=0;p<4;p++)
        nodesn[(((size_t)(b)<<HWSH) + px + p)*240 + o] = bf16rne(v[p]);
    }
  } else {
    const int r2 = blockIdx.x - 1536;
    const int chunk = r2 & 31;
    const int og    = r2 >> 5;             // 8 groups of 5 oc
    const int b   = chunk >> 4;
    const int px  = ((chunk & 15) << 8) + (lane << 2);
    const int o0  = og*5;
    float acc[4][5];
    #pragma unroll
    for (int p=0;p<4;p++)
      #pragma unroll
      for (int j=0;j<5;j++) acc[p][j]=0.f;
    const float* srcs[3] = {xp, xh, xf};
    #pragma unroll 1
    for (int part=0;part<3;part++){
      const float* xb = srcs[part] + (((size_t)b)<<20) + px;
      const float* wp = bgwt + part*256*40 + o0;
      #pragma unroll 1
      for (int c8=0;c8<32;c8++){
        float xv[8][4];
        #pragma unroll
        for (int j=0;j<8;j++)
          *(float4*)&xv[j][0] = *(const float4*)(xb + (((size_t)(c8*8+j))<<HWSH));
        #pragma unroll
        for (int j=0;j<8;j++){
          const float* wr = wp + (c8*8+j)*40;
          #pragma unroll
          for (int jj=0;jj<5;jj++){
            float w = wr[jj];
            #pragma unroll
            for (int p=0;p<4;p++) acc[p][jj] = fmaf(xv[j][p], w, acc[p][jj]);
          }
        }
      }
    }
    #pragma unroll
    for (int j=0;j<5;j++){
      int o = o0+j;
      float g = gg[o], bb = gb[o];
      float v[4];
      #pragma unroll
      for (int p=0;p<4;p++) v[p] = relu_(g*acc[p][j]+bb);
      *(float4*)&bg[(((size_t)(b*40+o))<<HWSH) + px] = *(float4*)v;
    }
  }
}

// ---- offsets conv 3x3 SAME: 80ch -> 27ch, ILP-8 channel blocking ----
// grid 1280 = e*128 + b*64 + h; block 256 = 64 px * 4 waves (7/7/7/6 oc).
// Per chunk: 24 independent row loads (8 ch x 3 ky) -> 8x63 FMA burst.
template<int STAGE>
__global__ __launch_bounds__(256) void k_off(
    const float* __restrict__ nodes, const float* __restrict__ h1,
    const float* __restrict__ wot, const float* __restrict__ bo,
    float* __restrict__ om)
{
  const int bid = blockIdx.x;
  const int e = bid >> 7;
  const int b = (bid >> 6) & 1;
  const int h = bid & 63;
  const int p = threadIdx.x & 63;
  const int wv = __builtin_amdgcn_readfirstlane(threadIdx.x >> 6);
  const int o0 = wv*7;
  const int no = (wv==3) ? 6 : 7;
  const int sn = c_src[e], dn = c_dst[e];
  const bool hm_ok = (h > 0), hp_ok = (h < 63);
  float acc[7];
  #pragma unroll
  for (int j=0;j<7;j++) acc[j] = (j<no) ? bo[e*27+o0+j] : 0.f;
  #pragma unroll 1
  for (int c8=0;c8<10;c8++){
    // ---- batch-load 8 channels x 3 rows (24 loads in flight) ----
    float xv[8][3];
    #pragma unroll
    for (int j=0;j<8;j++){
      const int c = c8*8+j;
      const float* cb;
      if (STAGE==1){
        int cc = (c<40) ? (sn*40+c) : (dn*40+c-40);
        cb = nodes + (((size_t)(b*240+cc))<<HWSH);
      } else {
        cb = h1 + (((size_t)((e*2+b)*80+c))<<HWSH);
      }
      xv[j][0] = hm_ok ? cb[((h-1)<<6)+p] : 0.f;
      xv[j][1] = cb[(h<<6)+p];
      xv[j][2] = hp_ok ? cb[((h+1)<<6)+p] : 0.f;
    }
    // ---- compute: per channel per ky, 2 shfl + 21 FMA ----
    #pragma unroll
    for (int j=0;j<8;j++){
      const float* wc = wot + (size_t)((e*80+c8*8+j)*9)*27 + o0;
      #pragma unroll
      for (int ky=0;ky<3;ky++){
        float x0 = xv[j][ky];
        float xm = __shfl_up(x0, 1);
        float xq = __shfl_down(x0, 1);
        xm = (p>0)  ? xm : 0.f;
        xq = (p<63) ? xq : 0.f;
        const float* wr = wc + ky*81;
        #pragma unroll
        for (int jj=0;jj<7;jj++){
          acc[jj] = fmaf(xm, wr[jj],    acc[jj]);
          acc[jj] = fmaf(x0, wr[27+jj], acc[jj]);
          acc[jj] = fmaf(xq, wr[54+jj], acc[jj]);
        }
      }
    }
  }
  const int off = (h<<6)+p;
  for (int j=0;j<no;j++)
    om[(((size_t)((e*2+b)*27 + o0 + j))<<HWSH)+off] = acc[j];
}

// ======== k_dcn: 1-wave blocks, bf16-NHWC uint4 gather + MFMA conv =========
// grid 5120 = e*512 + b*256 + h*4 + wv; block 64 = one wave.
template<int STAGE>
__global__ __launch_bounds__(64, 4) void k_dcn(
    const unsigned short* __restrict__ nodesn, const unsigned short* __restrict__ h1n,
    const float* __restrict__ om, const unsigned short* __restrict__ bs,
    const float* __restrict__ bng, const float* __restrict__ bnb,
    const float* __restrict__ attw, const float* __restrict__ attb,
    float* __restrict__ outp, unsigned short* __restrict__ outp2)
{
  constexpr int NT = (STAGE==1) ? 5 : 3;
  constexpr int CS = (STAGE==1) ? 240 : 80;     // NHWC channel stride (ushorts)
  const int bid = blockIdx.x;
  const int e  = bid >> 9;
  const int b  = (bid >> 8) & 1;
  const int h  = (bid >> 2) & 63;
  const int wv = bid & 3;
  const int lane = threadIdx.x;
  const int l15 = lane & 15;
  const int lg  = lane >> 4;
  const int px  = (wv<<4) + l15;
  const int off_px = (h<<6) + px;
  const int sn = c_src[e], dn = c_dst[e];

  const float* ombase = om + (((size_t)((e*2+b)*27))<<HWSH) + off_px;

  // per-lane group base pointers (group g = concat-ch [g*32+lg*8, +8))
  const unsigned short* gbase0; const unsigned short* gbase1; const unsigned short* gbase2;
  {
    const unsigned short* t[3];
    #pragma unroll
    for (int g=0; g<3; g++){
      int cg = g*32 + lg*8;
      if (STAGE==1){
        int cc = (cg < 40) ? (sn*40 + cg) : (dn*40 + cg - 40);
        t[g] = nodesn + ((size_t)(b)<<HWSH)*240 + cc;
      } else {
        t[g] = h1n + ((size_t)(e*2+b)<<HWSH)*80 + cg;
      }
    }
    gbase0 = t[0]; gbase1 = t[1]; gbase2 = t[2];
  }

  // stage2: per-lane attention factor for pixel px (bf16 NHWC: 5 uint4 loads)
  float attf = 0.f;
  if (STAGE==2){
    float at = attb[e];
    const unsigned short* nb = nodesn + (((size_t)(b)<<HWSH) + off_px)*240 + sn*40;
    #pragma unroll
    for (int q5=0;q5<5;q5++){
      uint4v q = *(const uint4v*)(nb + q5*8);
      #pragma unroll
      for (int u=0;u<4;u++){
        at = fmaf(bf16lo(q[u]), attw[e*40+q5*8+2*u],   at);
        at = fmaf(bf16hi(q[u]), attw[e*40+q5*8+2*u+1], at);
      }
    }
    attf = 2.f - sigm_(at);
  }

  f32x4 acc[NT];
  #pragma unroll
  for (int nt=0;nt<NT;nt++)
    #pragma unroll
    for (int r=0;r<4;r++) acc[nt][r] = 0.f;

  const unsigned short* bsk = bs + (size_t)e*9*3*NT*512;

  // om prefetch pipeline: (dy,dx,m) for tap k loaded one iteration ahead
  float dyc = ombase[0];
  float dxc = ombase[(size_t)1<<HWSH];
  float mrc = ombase[(size_t)18<<HWSH];

  #pragma unroll 1
  for (int k=0;k<9;k++){
    float dyn, dxn, mrn;
    if (k < 8){
      dyn = ombase[((size_t)(2*k+2))<<HWSH];
      dxn = ombase[((size_t)(2*k+3))<<HWSH];
      mrn = ombase[((size_t)(19+k))<<HWSH];
    }
    float mv  = sigm_(mrc);
    int ky = k/3, kx = k - 3*ky;
    float py  = dyc + (float)(ky - 1 + h);
    float pxf = dxc + (float)(kx - 1) + (float)px;
    float y0f = floorf(py), x0f = floorf(pxf);
    float wy = py - y0f, wx = pxf - x0f;
    int y0 = (int)y0f, x0i = (int)x0f;
    int y1 = y0+1, x1i = x0i+1;
    bool yv0 = (y0>=0)&&(y0<64),  yv1 = (y1>=0)&&(y1<64);
    bool xv0 = (x0i>=0)&&(x0i<64), xv1 = (x1i>=0)&&(x1i<64);
    float w00 = (yv0&&xv0) ? (1.f-wy)*(1.f-wx)*mv : 0.f;
    float w01 = (yv0&&xv1) ? (1.f-wy)*wx*mv       : 0.f;
    float w10 = (yv1&&xv0) ? wy*(1.f-wx)*mv       : 0.f;
    float w11 = (yv1&&xv1) ? wy*wx*mv             : 0.f;
    int yc0 = min(max(y0 ,0),63), yc1 = min(max(y1 ,0),63);
    int xc0 = min(max(x0i,0),63), xc1 = min(max(x1i,0),63);
    size_t a00 = (size_t)((yc0<<6)+xc0)*CS, a01 = (size_t)((yc0<<6)+xc1)*CS;
    size_t a10 = (size_t)((yc1<<6)+xc0)*CS, a11 = (size_t)((yc1<<6)+xc1)*CS;

    // ---- per group: 4 uint4 loads (4 corners x 8 bf16 ch) -> frags ----
    #pragma unroll
    for (int g=0; g<3; g++){
      const unsigned short* gb = (g==0) ? gbase0 : (g==1) ? gbase1 : gbase2;
      const bool active = (g < 2) || (lg < 2);   // K-pad 80..95 -> zero frags
      union { unsigned int u[4]; short8 v; } ah, al;
      if (active){
        uint4v q00 = *(const uint4v*)(gb + a00);
        uint4v q01 = *(const uint4v*)(gb + a01);
        uint4v q10 = *(const uint4v*)(gb + a10);
        uint4v q11 = *(const uint4v*)(gb + a11);
        #pragma unroll
        for (int u=0;u<4;u++){
          float s0 = fmaf(w00,bf16lo(q00[u]), fmaf(w01,bf16lo(q01[u]),
                       fmaf(w10,bf16lo(q10[u]), w11*bf16lo(q11[u]))));
          float s1 = fmaf(w00,bf16hi(q00[u]), fmaf(w01,bf16hi(q01[u]),
                       fmaf(w10,bf16hi(q10[u]), w11*bf16hi(q11[u]))));
          unsigned short h0 = bf16rne(s0), h1_ = bf16rne(s1);
          unsigned short l0 = bf16rne(s0 - bf16f(h0)), l1 = bf16rne(s1 - bf16f(h1_));
          ah.u[u] = (unsigned int)h0 | ((unsigned int)h1_<<16);
          al.u[u] = (unsigned int)l0 | ((unsigned int)l1<<16);
        }
      } else {
        ah.u[0]=ah.u[1]=ah.u[2]=ah.u[3]=0u;
        al.u[0]=al.u[1]=al.u[2]=al.u[3]=0u;
      }
      #pragma unroll
      for (int nt=0;nt<NT;nt++){
        union { unsigned int u[4]; short8 v; } bf;
        const unsigned int* pb2 = (const unsigned int*)
          (bsk + ((size_t)((g*NT + nt)*64 + lane))*8);
        bf.u[0]=pb2[0]; bf.u[1]=pb2[1]; bf.u[2]=pb2[2]; bf.u[3]=pb2[3];
        acc[nt] = __builtin_amdgcn_mfma_f32_16x16x32_bf16(ah.v, bf.v, acc[nt], 0,0,0);
        acc[nt] = __builtin_amdgcn_mfma_f32_16x16x32_bf16(al.v, bf.v, acc[nt], 0,0,0);
      }
    }
    bsk += 3*NT*512;
    dyc = dyn; dxc = dxn; mrc = mrn;
  }

  // ---- epilogue: D col n = nt*16+l15, row -> pixel = 16wv + lg*4 + r ----
  if (STAGE==1){
    #pragma unroll
    for (int nt=0;nt<NT;nt++){
      int n = nt*16 + l15;
      float g = bng[e*80+n], bb = bnb[e*80+n];
      #pragma unroll
      for (int r=0;r<4;r++){
        int pxs = (wv<<4) + lg*4 + r;
        float v = relu_(g*acc[nt][r] + bb);
        outp[(((size_t)((e*2+b)*80+n))<<HWSH) + (h<<6) + pxs] = v;              // NCHW fp32
        outp2[(((size_t)(e*2+b)<<HWSH) + (h<<6) + pxs)*80 + n] = bf16rne(v);     // NHWC bf16
      }
    }
  } else {
    // DIVERGENCE-SAFE: shfl with ALL lanes active, BEFORE the n<40 guard.
    float fac[4];
    #pragma unroll
    for (int r=0;r<4;r++) fac[r] = __shfl(attf, 4*lg + r, 64);
    #pragma unroll
    for (int nt=0;nt<NT;nt++){
      int n = nt*16 + l15;
      if (n < 40){
        float g = bng[e*40+n], bb = bnb[e*40+n];
        #pragma unroll
        for (int r=0;r<4;r++){
          int pxs = (wv<<4) + lg*4 + r;
          float v = relu_(g*acc[nt][r] + bb) * fac[r];
          atomicAdd(&outp[(((size_t)(dn*2+b)<<HWSH) + (h<<6) + pxs)*40 + n], v);  // fp32 msgs
        }
      }
    }
  }
}

// ---- node update: 2-layer 1x1 MLP; nodesn bf16, msgs fp32 -> newbn NCHW ----
__global__ __launch_bounds__(128) void k_upd(
    const unsigned short* __restrict__ nodesn, const float* __restrict__ msgs,
    const float* __restrict__ uw1t, const float* __restrict__ g1, const float* __restrict__ b1,
    const float* __restrict__ uw2t, const float* __restrict__ g2, const float* __restrict__ b2,
    float* __restrict__ newbn)
{
  const int bid = blockIdx.x;
  const int n = bid >> 6;
  const int r = bid & 63;
  const int b = r >> 5;
  const int pix = ((r & 31) << 7) + threadIdx.x;
  float a1[32];
  #pragma unroll
  for (int j=0;j<32;j++) a1[j]=0.f;
  // node features: 40 bf16 = 5 x uint4 loads
  {
    const unsigned short* nb = nodesn + (((size_t)(b)<<HWSH) + pix)*240 + n*40;
    float xv[40];
    #pragma unroll
    for (int q5=0;q5<5;q5++){
      uint4v q = *(const uint4v*)(nb + q5*8);
      #pragma unroll
      for (int u=0;u<4;u++){ xv[q5*8+2*u] = bf16lo(q[u]); xv[q5*8+2*u+1] = bf16hi(q[u]); }
    }
    #pragma unroll 4
    for (int c=0;c<40;c++){
      const float* wr = uw1t + (n*80 + c)*32;
      float x = xv[c];
      #pragma unroll
      for (int j=0;j<32;j++) a1[j]=fmaf(x,wr[j],a1[j]);
    }
  }
  const float* mb = msgs + (((size_t)(n*2+b)<<HWSH) + pix)*40;
  #pragma unroll 2
  for (int c4=0;c4<10;c4++){
    float xv[4];
    *(float4*)xv = *(const float4*)(mb + c4*4);
    #pragma unroll
    for (int ee=0;ee<4;ee++){
      const float* wr = uw1t + (n*80+40 + c4*4+ee)*32;
      #pragma unroll
      for (int j=0;j<32;j++) a1[j]=fmaf(xv[ee],wr[j],a1[j]);
    }
  }
  #pragma unroll
  for (int j=0;j<32;j++) a1[j] = relu_(g1[n*32+j]*a1[j]+b1[n*32+j]);
  float a2[40];
  #pragma unroll
  for (int j=0;j<40;j++) a2[j]=0.f;
  for (int c=0;c<32;c++){
    const float* wr = uw2t + (n*32+c)*40;
    #pragma unroll
    for (int j=0;j<40;j++) a2[j]=fmaf(a1[c],wr[j],a2[j]);
  }
  #pragma unroll
  for (int j=0;j<40;j++)
    newbn[(((size_t)(b*240+n*40+j))<<HWSH)+pix] = relu_(g2[n*40+j]*a2[j]+b2[n*40+j]);
}

// ======== k_post: xp_infer concat (4288 blocks) + pg classifier (224) ====
__global__ __launch_bounds__(256) void k_post(
    const float* __restrict__ xp, const float* __restrict__ bg,
    const float* __restrict__ newbn, const float* __restrict__ nodes,
    const float* __restrict__ cw, const float* __restrict__ cb,
    const float* __restrict__ cnw, const float* __restrict__ cnb,
    float* __restrict__ out)
{
  if (blockIdx.x < 4288){
    int i4 = blockIdx.x*256+threadIdx.x;   // exactly 1097728
    int idx = i4 << 2;
    int b = idx / (536*4096);
    int r = idx - b*(536*4096);
    int ch = r >> HWSH;
    int off = r & 4095;
    float4 v;
    if (ch < 256)      v = *(const float4*)&xp[(((size_t)(b*256+ch))<<HWSH)+off];
    else if (ch < 296) v = *(const float4*)&bg[(((size_t)(b*40+ch-256))<<HWSH)+off];
    else               v = *(const float4*)&newbn[(((size_t)(b*240+ch-296))<<HWSH)+off];
    *(float4*)&out[idx] = v;
  } else {
    int idx = (blockIdx.x-4288)*256+threadIdx.x;   // exactly 57344
    int b = idx / (7*4096);
    int r = idx - b*7*4096;
    int g = r >> HWSH;
    int off = r & 4095;
    float a = cb[g] + cnb[g];
    if (g == 0){
      for (int c=0;c<40;c++){
        float v = bg[(((size_t)(b*40+c))<<HWSH)+off];
        a = fmaf(v, cw[c]+cnw[c], a);
      }
    } else {
      for (int c=0;c<40;c++){
        float vo = nodes[(((size_t)(b*240+(g-1)*40+c))<<HWSH)+off];
        float vn = newbn[(((size_t)(b*240+(g-1)*40+c))<<HWSH)+off];
        a = fmaf(vo, cw[g*40+c], a);
        a = fmaf(vn, cnw[g*40+c], a);
      }
    }
    out[4390912 + idx] = a;
  }
}

extern "C" void kernel_launch(void* const* d_in, const int* in_sizes, int n_in,
                              void* d_out, int out_size, void* d_ws, size_t ws_size,
                              hipStream_t stream)
{
  const float* xp       = (const float*)d_in[0];
  const float* xh       = (const float*)d_in[1];
  const float* xf       = (const float*)d_in[2];
  const float* p_w      = (const float*)d_in[3];
  const float* p_g      = (const float*)d_in[4];
  const float* p_b      = (const float*)d_in[5];
  const float* bg_w     = (const float*)d_in[6];
  const float* bg_g     = (const float*)d_in[7];
  const float* bg_b     = (const float*)d_in[8];
  const float* e_off1_w = (const float*)d_in[9];
  const float* e_off1_b = (const float*)d_in[10];
  const float* e_dcn1_w = (const float*)d_in[11];
  const float* e_bn1_g  = (const float*)d_in[12];
  const float* e_bn1_b  = (const float*)d_in[13];
  const float* e_off2_w = (const float*)d_in[14];
  const float* e_off2_b = (const float*)d_in[15];
  const float* e_dcn2_w = (const float*)d_in[16];
  const float* e_bn2_g  = (const float*)d_in[17];
  const float* e_bn2_b  = (const float*)d_in[18];
  const float* e_att_w  = (const float*)d_in[19];
  const float* e_att_b  = (const float*)d_in[20];
  const float* u_w1     = (const float*)d_in[21];
  const float* u_g1     = (const float*)d_in[22];
  const float* u_b1     = (const float*)d_in[23];
  const float* u_w2     = (const float*)d_in[24];
  const float* u_g2     = (const float*)d_in[25];
  const float* u_b2     = (const float*)d_in[26];
  const float* cls_w    = (const float*)d_in[27];
  const float* cls_b    = (const float*)d_in[28];
  const float* cls_nw   = (const float*)d_in[29];
  const float* cls_nb   = (const float*)d_in[30];

  float* ws     = (float*)d_ws;
  float* nodes  = ws + NODES_OFF;
  unsigned short* nodesn = (unsigned short*)(ws + NODESN_OFF);
  float* bgb    = ws + BG_OFF;
  float* h1     = ws + H1_OFF;
  unsigned short* h1n = (unsigned short*)(ws + H1N_OFF);
  float* om     = ws + OM_OFF;
  float* msgs   = ws + MSGS_OFF;
  float* newbn  = ws + NEWBN_OFF;
  float* wo1t   = ws + WO1T_OFF;
  float* wo2t   = ws + WO2T_OFF;
  float* pwt    = ws + PWT_OFF;
  float* bgwt   = ws + BGWT_OFF;
  float* uw1t   = ws + UW1T_OFF;
  float* uw2t   = ws + UW2T_OFF;
  const unsigned short* bs1u = (const unsigned short*)(ws + BS1_OFF);
  const unsigned short* bs2u = (const unsigned short*)(ws + BS2_OFF);

  hipMemsetAsync(msgs, 0, (size_t)1966080*sizeof(float), stream);
  k_pre<<<2510, 256, 0, stream>>>(e_off1_w, e_off2_w, p_w, bg_w, u_w1, u_w2,
                                  e_dcn1_w, e_dcn2_w, ws);
  k_gemm1<<<1792, 64, 0, stream>>>(xp, xh, xf, pwt, p_g, p_b, bgwt, bg_g, bg_b,
                                   nodes, nodesn, bgb);
  k_off<1><<<1280, 256, 0, stream>>>(nodes, nullptr, wo1t, e_off1_b, om);
  k_dcn<1><<<5120, 64, 0, stream>>>(nodesn, nullptr, om, bs1u, e_bn1_g, e_bn1_b,
                                    nullptr, nullptr, h1, h1n);
  k_off<2><<<1280, 256, 0, stream>>>(nullptr, h1, wo2t, e_off2_b, om);
  k_dcn<2><<<5120, 64, 0, stream>>>(nodesn, h1n, om, bs2u, e_bn2_g, e_bn2_b,
                                    e_att_w, e_att_b, msgs, nullptr);
  k_upd<<<384, 128, 0, stream>>>(nodesn, msgs, uw1t, u_g1, u_b1, uw2t, u_g2, u_b2, newbn);
  k_post<<<4512, 256, 0, stream>>>(xp, bgb, newbn, nodes, cls_w, cls_b, cls_nw, cls_nb,
                                   (float*)d_out);
}

// Round 19
// 450.946 us; speedup vs baseline: 1.0303x; 1.0303x over previous
//
#include <hip/hip_runtime.h>
#include <math.h>

// Decoder_9887014716020 — R18: k_off with per-wave CONTIGUOUS weight layout
// wo[e][wv][c][9][7] (63 floats/ch/wave, streamable s_load_dwordx16) +
// simple R16 loop body (ILP-8 batching regressed; kernel was SMEM-stream
// bound, not gather-bound). Rest identical to R17/R16 best build.
// B=2, H=W=64 (HW=4096), HD=40, N_NODES=6, 10 edges.

#define HWSH 12      // 4096 = 1<<12

__device__ __constant__ int c_src[10] = {0,1,1,1,2,2,3,4,4,5};
__device__ __constant__ int c_dst[10] = {1,0,2,4,1,3,2,1,5,4};

typedef __attribute__((ext_vector_type(8))) short short8;
typedef __attribute__((ext_vector_type(4))) float f32x4;
typedef __attribute__((ext_vector_type(4))) unsigned int uint4v;

// ---- workspace layout (float offsets; NODESN/H1N reinterpreted as ushort) --
constexpr size_t NODES_OFF  = 0;          // NCHW 2*240*4096 fp32
constexpr size_t NODESN_OFF = 1966080;    // NHWC [b][4096][240] BF16 (ushort)
constexpr size_t BG_OFF     = 3932160;    // 2*40*4096
constexpr size_t H1_OFF     = 4259840;    // NCHW 20*80*4096 fp32
constexpr size_t H1N_OFF    = 10813440;   // NHWC [20][4096][80] BF16 (ushort)
constexpr size_t OM_OFF     = 17367040;   // 10*2*27*4096
constexpr size_t MSGS_OFF   = 19578880;   // NHWC [6*2][4096][40] fp32
constexpr size_t NEWBN_OFF  = 21544960;   // NCHW 2*240*4096
constexpr size_t BS1_OFF    = 23511040;   // bf16 B-frags s1: 691200 ushort
constexpr size_t BS2_OFF    = 23856640;   // s2: 414720 ushort
constexpr size_t WO1T_OFF   = 24064000;   // 10*4*80*63 = 201600
constexpr size_t WO2T_OFF   = 24265600;   // 201600
constexpr size_t PWT_OFF    = 24467200;   // 256*240 = 61440
constexpr size_t BGWT_OFF   = 24528640;   // 768*40 = 30720
constexpr size_t UW1T_OFF   = 24559360;   // 6*80*32 = 15360
constexpr size_t UW2T_OFF   = 24574720;   // 6*32*40 = 7680 -> end 24,582,400

__device__ inline float relu_(float x){ return x > 0.f ? x : 0.f; }
__device__ inline float sigm_(float x){ return 1.f/(1.f + __expf(-x)); }
__device__ inline unsigned short bf16rne(float x){
  unsigned int u = __float_as_uint(x);
  unsigned int r = (u + 0x7fffu + ((u>>16)&1u)) >> 16;
  return (unsigned short)r;
}
__device__ inline float bf16f(unsigned short h){
  return __uint_as_float(((unsigned int)h)<<16);
}
__device__ inline float bf16lo(unsigned int u){ return __uint_as_float(u<<16); }
__device__ inline float bf16hi(unsigned int u){ return __uint_as_float(u & 0xffff0000u); }

// ======== k_pre: weight transposes + bf16 B-fragment prepack ===============
// [0,2025): transposes | [2025,2363): bs1 | [2363,2566): bs2
__global__ __launch_bounds__(256) void k_pre(
    const float* __restrict__ off1w, const float* __restrict__ off2w,
    const float* __restrict__ p_w,  const float* __restrict__ bg_w,
    const float* __restrict__ u_w1, const float* __restrict__ u_w2,
    const float* __restrict__ dcn1w, const float* __restrict__ dcn2w,
    float* __restrict__ ws)
{
  const int bid = blockIdx.x;
  const int tid = threadIdx.x;
  if (bid < 2025){
    int i = bid*256 + tid;
    if (i < 201600){                       // wo1t[e][wv][c][t][jj]
      int jj = i % 7; int t = (i/7) % 9; int c = (i/63) % 80;
      int wv = (i/5040) % 4; int e = i/20160;
      int oc = wv*7 + jj;
      ws[WO1T_OFF+i] = (oc < 27) ? off1w[(size_t)((e*27+oc)*80+c)*9+t] : 0.f;
    } else if (i < 403200){                // wo2t same layout
      int j = i-201600;
      int jj = j % 7; int t = (j/7) % 9; int c = (j/63) % 80;
      int wv = (j/5040) % 4; int e = j/20160;
      int oc = wv*7 + jj;
      ws[WO2T_OFF+j] = (oc < 27) ? off2w[(size_t)((e*27+oc)*80+c)*9+t] : 0.f;
    } else if (i < 464640){                // pwt[c][o]
      int j = i-403200;
      int o=j%240; int c=j/240;
      ws[PWT_OFF+j] = p_w[(size_t)o*256+c];
    } else if (i < 495360){                // bgwt[c][o]
      int j = i-464640;
      int o=j%40; int c=j/40;
      ws[BGWT_OFF+j] = bg_w[(size_t)o*768+c];
    } else if (i < 510720){                // uw1t[n][c][o]
      int j = i-495360;
      int o=j%32; int t2=j/32; int c=t2%80; int n=t2/80;
      ws[UW1T_OFF+j] = u_w1[(size_t)((n*32+o)*80)+c];
    } else if (i < 518400){                // uw2t[n][c][o]
      int j = i-510720;
      int o=j%40; int t2=j/40; int c=t2%32; int n=t2/32;
      ws[UW2T_OFF+j] = u_w2[(size_t)((n*40+o)*32)+c];
    }
  } else if (bid < 2363){
    // bs1: q = ((e*9+k)*3+kst)*5+nt, per lane 8 bf16
    int t = (bid-2025)*256 + tid;
    if (t < 86400){
      int lane = t & 63; int q = t >> 6;
      int nt = q % 5; int q2 = q/5; int kst = q2 % 3; q2/=3; int k = q2 % 9; int e = q2/9;
      int n  = nt*16 + (lane & 15);
      int c0 = kst*32 + (lane>>4)*8;
      union { unsigned int u[4]; } r;
      unsigned short v[8];
      #pragma unroll
      for (int j=0;j<8;j++){
        int c = c0 + j;
        float w = (c < 80) ? dcn1w[(size_t)((e*80+n)*80+c)*9+k] : 0.f;
        v[j] = bf16rne(w);
      }
      #pragma unroll
      for (int j=0;j<4;j++) r.u[j] = (unsigned int)v[2*j] | ((unsigned int)v[2*j+1]<<16);
      unsigned int* dst = (unsigned int*)((unsigned short*)(ws + BS1_OFF) + (size_t)t*8);
      dst[0]=r.u[0]; dst[1]=r.u[1]; dst[2]=r.u[2]; dst[3]=r.u[3];
    }
  } else {
    // bs2: q = ((e*9+k)*3+kst)*3+nt
    int t = (bid-2363)*256 + tid;
    if (t < 51840){
      int lane = t & 63; int q = t >> 6;
      int nt = q % 3; int q2 = q/3; int kst = q2 % 3; q2/=3; int k = q2 % 9; int e = q2/9;
      int n  = nt*16 + (lane & 15);
      int c0 = kst*32 + (lane>>4)*8;
      union { unsigned int u[4]; } r;
      unsigned short v[8];
      #pragma unroll
      for (int j=0;j<8;j++){
        int c = c0 + j;
        float w = (n < 40 && c < 80) ? dcn2w[(size_t)((e*40+n)*80+c)*9+k] : 0.f;
        v[j] = bf16rne(w);
      }
      #pragma unroll
      for (int j=0;j<4;j++) r.u[j] = (unsigned int)v[2*j] | ((unsigned int)v[2*j+1]<<16);
      unsigned int* dst = (unsigned int*)((unsigned short*)(ws + BS2_OFF) + (size_t)t*8);
      dst[0]=r.u[0]; dst[1]=r.u[1]; dst[2]=r.u[2]; dst[3]=r.u[3];
    }
  }
}

// ======== k_gemm1 v4: ILP-8 blocked loads; NHWC mirror stored bf16 =========
__global__ __launch_bounds__(64, 4) void k_gemm1(
    const float* __restrict__ xp, const float* __restrict__ xh, const float* __restrict__ xf,
    const float* __restrict__ pwt, const float* __restrict__ pg, const float* __restrict__ pb_,
    const float* __restrict__ bgwt, const float* __restrict__ gg, const float* __restrict__ gb,
    float* __restrict__ nodes, unsigned short* __restrict__ nodesn, float* __restrict__ bg)
{
  const int lane = threadIdx.x;
  if (blockIdx.x < 1536){
    const int chunk = blockIdx.x & 31;     // 32 chunks of 256 px (2 batches)
    const int og    = blockIdx.x >> 5;     // 48 groups of 5 oc
    const int b   = chunk >> 4;
    const int px  = ((chunk & 15) << 8) + (lane << 2);
    const int o0  = og*5;
    float acc[4][5];
    #pragma unroll
    for (int p=0;p<4;p++)
      #pragma unroll
      for (int j=0;j<5;j++) acc[p][j]=0.f;
    const float* xb = xp + (((size_t)b)<<20) + px;
    #pragma unroll 1
    for (int c8=0;c8<32;c8++){
      float xv[8][4];
      #pragma unroll
      for (int j=0;j<8;j++)
        *(float4*)&xv[j][0] = *(const float4*)(xb + (((size_t)(c8*8+j))<<HWSH));
      #pragma unroll
      for (int j=0;j<8;j++){
        const float* wr = pwt + (c8*8+j)*240 + o0;
        #pragma unroll
        for (int jj=0;jj<5;jj++){
          float w = wr[jj];
          #pragma unroll
          for (int p=0;p<4;p++) acc[p][jj] = fmaf(xv[j][p], w, acc[p][jj]);
        }
      }
    }
    #pragma unroll
    for (int j=0;j<5;j++){
      int o = o0+j;
      float g = pg[o], bb = pb_[o];
      float v[4];
      #pragma unroll
      for (int p=0;p<4;p++) v[p] = relu_(g*acc[p][j]+bb);
      *(float4*)&nodes[(((size_t)(b*240+o))<<HWSH) + px] = *(float4*)v;
      #pragma unroll
      for (int p=0;p<4;p++)
        nodesn[(((size_t)(b)<<HWSH) + px + p)*240 + o] = bf16rne(v[p]);
    }
  } else {
    const int r2 = blockIdx.x - 1536;
    const int chunk = r2 & 31;
    const int og    = r2 >> 5;             // 8 groups of 5 oc
    const int b   = chunk >> 4;
    const int px  = ((chunk & 15) << 8) + (lane << 2);
    const int o0  = og*5;
    float acc[4][5];
    #pragma unroll
    for (int p=0;p<4;p++)
      #pragma unroll
      for (int j=0;j<5;j++) acc[p][j]=0.f;
    const float* srcs[3] = {xp, xh, xf};
    #pragma unroll 1
    for (int part=0;part<3;part++){
      const float* xb = srcs[part] + (((size_t)b)<<20) + px;
      const float* wp = bgwt + part*256*40 + o0;
      #pragma unroll 1
      for (int c8=0;c8<32;c8++){
        float xv[8][4];
        #pragma unroll
        for (int j=0;j<8;j++)
          *(float4*)&xv[j][0] = *(const float4*)(xb + (((size_t)(c8*8+j))<<HWSH));
        #pragma unroll
        for (int j=0;j<8;j++){
          const float* wr = wp + (c8*8+j)*40;
          #pragma unroll
          for (int jj=0;jj<5;jj++){
            float w = wr[jj];
            #pragma unroll
            for (int p=0;p<4;p++) acc[p][jj] = fmaf(xv[j][p], w, acc[p][jj]);
          }
        }
      }
    }
    #pragma unroll
    for (int j=0;j<5;j++){
      int o = o0+j;
      float g = gg[o], bb = gb[o];
      float v[4];
      #pragma unroll
      for (int p=0;p<4;p++) v[p] = relu_(g*acc[p][j]+bb);
      *(float4*)&bg[(((size_t)(b*40+o))<<HWSH) + px] = *(float4*)v;
    }
  }
}

// ---- offsets conv 3x3 SAME: 80ch -> 27ch; per-wave contiguous weights ----
// wot layout: [e][wv][c][tap 0..8][7]; wave reads 63 contiguous floats per ch.
template<int STAGE>
__global__ __launch_bounds__(256) void k_off(
    const float* __restrict__ nodes, const float* __restrict__ h1,
    const float* __restrict__ wot, const float* __restrict__ bo,
    float* __restrict__ om)
{
  const int bid = blockIdx.x;
  const int e = bid >> 7;
  const int b = (bid >> 6) & 1;
  const int h = bid & 63;
  const int p = threadIdx.x & 63;
  const int wv = __builtin_amdgcn_readfirstlane(threadIdx.x >> 6);
  const int o0 = wv*7;
  const int no = (wv==3) ? 6 : 7;
  const int sn = c_src[e], dn = c_dst[e];
  float acc[7];
  #pragma unroll
  for (int j=0;j<7;j++) acc[j] = (j<no) ? bo[e*27+o0+j] : 0.f;
  const float* wcbase = wot + (size_t)((e*4+wv)*80)*63;
  #pragma unroll 2
  for (int c=0;c<80;c++){
    const float* cb;
    if (STAGE==1){
      int cc = (c<40) ? (sn*40+c) : (dn*40+c-40);
      cb = nodes + (((size_t)(b*240+cc))<<HWSH);
    } else {
      cb = h1 + (((size_t)((e*2+b)*80+c))<<HWSH);
    }
    const float* wc = wcbase + c*63;
    #pragma unroll
    for (int ky=0;ky<3;ky++){
      int hy = h+ky-1;
      if (hy < 0 || hy > 63) continue;
      float x0 = cb[(hy<<6) + p];
      float xm = __shfl_up(x0, 1);
      float xq = __shfl_down(x0, 1);
      xm = (p>0)  ? xm : 0.f;
      xq = (p<63) ? xq : 0.f;
      const float* wr = wc + ky*21;   // [tap ky*3+kx][7]: kx=0 at 0, 1 at 7, 2 at 14
      #pragma unroll
      for (int j=0;j<7;j++){
        acc[j] = fmaf(xm, wr[j],    acc[j]);
        acc[j] = fmaf(x0, wr[7+j],  acc[j]);
        acc[j] = fmaf(xq, wr[14+j], acc[j]);
      }
    }
  }
  const int off = (h<<6)+p;
  for (int j=0;j<no;j++)
    om[(((size_t)((e*2+b)*27 + o0 + j))<<HWSH)+off] = acc[j];
}

// ======== k_dcn: 1-wave blocks, bf16-NHWC uint4 gather + MFMA conv =========
// grid 5120 = e*512 + b*256 + h*4 + wv; block 64 = one wave.
template<int STAGE>
__global__ __launch_bounds__(64, 4) void k_dcn(
    const unsigned short* __restrict__ nodesn, const unsigned short* __restrict__ h1n,
    const float* __restrict__ om, const unsigned short* __restrict__ bs,
    const float* __restrict__ bng, const float* __restrict__ bnb,
    const float* __restrict__ attw, const float* __restrict__ attb,
    float* __restrict__ outp, unsigned short* __restrict__ outp2)
{
  constexpr int NT = (STAGE==1) ? 5 : 3;
  constexpr int CS = (STAGE==1) ? 240 : 80;     // NHWC channel stride (ushorts)
  const int bid = blockIdx.x;
  const int e  = bid >> 9;
  const int b  = (bid >> 8) & 1;
  const int h  = (bid >> 2) & 63;
  const int wv = bid & 3;
  const int lane = threadIdx.x;
  const int l15 = lane & 15;
  const int lg  = lane >> 4;
  const int px  = (wv<<4) + l15;
  const int off_px = (h<<6) + px;
  const int sn = c_src[e], dn = c_dst[e];

  const float* ombase = om + (((size_t)((e*2+b)*27))<<HWSH) + off_px;

  // per-lane group base pointers (group g = concat-ch [g*32+lg*8, +8))
  const unsigned short* gbase0; const unsigned short* gbase1; const unsigned short* gbase2;
  {
    const unsigned short* t[3];
    #pragma unroll
    for (int g=0; g<3; g++){
      int cg = g*32 + lg*8;
      if (STAGE==1){
        int cc = (cg < 40) ? (sn*40 + cg) : (dn*40 + cg - 40);
        t[g] = nodesn + ((size_t)(b)<<HWSH)*240 + cc;
      } else {
        t[g] = h1n + ((size_t)(e*2+b)<<HWSH)*80 + cg;
      }
    }
    gbase0 = t[0]; gbase1 = t[1]; gbase2 = t[2];
  }

  // stage2: per-lane attention factor for pixel px (bf16 NHWC: 5 uint4 loads)
  float attf = 0.f;
  if (STAGE==2){
    float at = attb[e];
    const unsigned short* nb = nodesn + (((size_t)(b)<<HWSH) + off_px)*240 + sn*40;
    #pragma unroll
    for (int q5=0;q5<5;q5++){
      uint4v q = *(const uint4v*)(nb + q5*8);
      #pragma unroll
      for (int u=0;u<4;u++){
        at = fmaf(bf16lo(q[u]), attw[e*40+q5*8+2*u],   at);
        at = fmaf(bf16hi(q[u]), attw[e*40+q5*8+2*u+1], at);
      }
    }
    attf = 2.f - sigm_(at);
  }

  f32x4 acc[NT];
  #pragma unroll
  for (int nt=0;nt<NT;nt++)
    #pragma unroll
    for (int r=0;r<4;r++) acc[nt][r] = 0.f;

  const unsigned short* bsk = bs + (size_t)e*9*3*NT*512;

  // om prefetch pipeline: (dy,dx,m) for tap k loaded one iteration ahead
  float dyc = ombase[0];
  float dxc = ombase[(size_t)1<<HWSH];
  float mrc = ombase[(size_t)18<<HWSH];

  #pragma unroll 1
  for (int k=0;k<9;k++){
    float dyn, dxn, mrn;
    if (k < 8){
      dyn = ombase[((size_t)(2*k+2))<<HWSH];
      dxn = ombase[((size_t)(2*k+3))<<HWSH];
      mrn = ombase[((size_t)(19+k))<<HWSH];
    }
    float mv  = sigm_(mrc);
    int ky = k/3, kx = k - 3*ky;
    float py  = dyc + (float)(ky - 1 + h);
    float pxf = dxc + (float)(kx - 1) + (float)px;
    float y0f = floorf(py), x0f = floorf(pxf);
    float wy = py - y0f, wx = pxf - x0f;
    int y0 = (int)y0f, x0i = (int)x0f;
    int y1 = y0+1, x1i = x0i+1;
    bool yv0 = (y0>=0)&&(y0<64),  yv1 = (y1>=0)&&(y1<64);
    bool xv0 = (x0i>=0)&&(x0i<64), xv1 = (x1i>=0)&&(x1i<64);
    float w00 = (yv0&&xv0) ? (1.f-wy)*(1.f-wx)*mv : 0.f;
    float w01 = (yv0&&xv1) ? (1.f-wy)*wx*mv       : 0.f;
    float w10 = (yv1&&xv0) ? wy*(1.f-wx)*mv       : 0.f;
    float w11 = (yv1&&xv1) ? wy*wx*mv             : 0.f;
    int yc0 = min(max(y0 ,0),63), yc1 = min(max(y1 ,0),63);
    int xc0 = min(max(x0i,0),63), xc1 = min(max(x1i,0),63);
    size_t a00 = (size_t)((yc0<<6)+xc0)*CS, a01 = (size_t)((yc0<<6)+xc1)*CS;
    size_t a10 = (size_t)((yc1<<6)+xc0)*CS, a11 = (size_t)((yc1<<6)+xc1)*CS;

    // ---- per group: 4 uint4 loads (4 corners x 8 bf16 ch) -> frags ----
    #pragma unroll
    for (int g=0; g<3; g++){
      const unsigned short* gb = (g==0) ? gbase0 : (g==1) ? gbase1 : gbase2;
      const bool active = (g < 2) || (lg < 2);   // K-pad 80..95 -> zero frags
      union { unsigned int u[4]; short8 v; } ah, al;
      if (active){
        uint4v q00 = *(const uint4v*)(gb + a00);
        uint4v q01 = *(const uint4v*)(gb + a01);
        uint4v q10 = *(const uint4v*)(gb + a10);
        uint4v q11 = *(const uint4v*)(gb + a11);
        #pragma unroll
        for (int u=0;u<4;u++){
          float s0 = fmaf(w00,bf16lo(q00[u]), fmaf(w01,bf16lo(q01[u]),
                       fmaf(w10,bf16lo(q10[u]), w11*bf16lo(q11[u]))));
          float s1 = fmaf(w00,bf16hi(q00[u]), fmaf(w01,bf16hi(q01[u]),
                       fmaf(w10,bf16hi(q10[u]), w11*bf16hi(q11[u]))));
          unsigned short h0 = bf16rne(s0), h1_ = bf16rne(s1);
          unsigned short l0 = bf16rne(s0 - bf16f(h0)), l1 = bf16rne(s1 - bf16f(h1_));
          ah.u[u] = (unsigned int)h0 | ((unsigned int)h1_<<16);
          al.u[u] = (unsigned int)l0 | ((unsigned int)l1<<16);
        }
      } else {
        ah.u[0]=ah.u[1]=ah.u[2]=ah.u[3]=0u;
        al.u[0]=al.u[1]=al.u[2]=al.u[3]=0u;
      }
      #pragma unroll
      for (int nt=0;nt<NT;nt++){
        union { unsigned int u[4]; short8 v; } bf;
        const unsigned int* pb2 = (const unsigned int*)
          (bsk + ((size_t)((g*NT + nt)*64 + lane))*8);
        bf.u[0]=pb2[0]; bf.u[1]=pb2[1]; bf.u[2]=pb2[2]; bf.u[3]=pb2[3];
        acc[nt] = __builtin_amdgcn_mfma_f32_16x16x32_bf16(ah.v, bf.v, acc[nt], 0,0,0);
        acc[nt] = __builtin_amdgcn_mfma_f32_16x16x32_bf16(al.v, bf.v, acc[nt], 0,0,0);
      }
    }
    bsk += 3*NT*512;
    dyc = dyn; dxc = dxn; mrc = mrn;
  }

  // ---- epilogue: D col n = nt*16+l15, row -> pixel = 16wv + lg*4 + r ----
  if (STAGE==1){
    #pragma unroll
    for (int nt=0;nt<NT;nt++){
      int n = nt*16 + l15;
      float g = bng[e*80+n], bb = bnb[e*80+n];
      #pragma unroll
      for (int r=0;r<4;r++){
        int pxs = (wv<<4) + lg*4 + r;
        float v = relu_(g*acc[nt][r] + bb);
        outp[(((size_t)((e*2+b)*80+n))<<HWSH) + (h<<6) + pxs] = v;              // NCHW fp32
        outp2[(((size_t)(e*2+b)<<HWSH) + (h<<6) + pxs)*80 + n] = bf16rne(v);     // NHWC bf16
      }
    }
  } else {
    // DIVERGENCE-SAFE: shfl with ALL lanes active, BEFORE the n<40 guard.
    float fac[4];
    #pragma unroll
    for (int r=0;r<4;r++) fac[r] = __shfl(attf, 4*lg + r, 64);
    #pragma unroll
    for (int nt=0;nt<NT;nt++){
      int n = nt*16 + l15;
      if (n < 40){
        float g = bng[e*40+n], bb = bnb[e*40+n];
        #pragma unroll
        for (int r=0;r<4;r++){
          int pxs = (wv<<4) + lg*4 + r;
          float v = relu_(g*acc[nt][r] + bb) * fac[r];
          atomicAdd(&outp[(((size_t)(dn*2+b)<<HWSH) + (h<<6) + pxs)*40 + n], v);  // fp32 msgs
        }
      }
    }
  }
}

// ---- node update: 2-layer 1x1 MLP; nodesn bf16, msgs fp32 -> newbn NCHW ----
__global__ __launch_bounds__(128) void k_upd(
    const unsigned short* __restrict__ nodesn, const float* __restrict__ msgs,
    const float* __restrict__ uw1t, const float* __restrict__ g1, const float* __restrict__ b1,
    const float* __restrict__ uw2t, const float* __restrict__ g2, const float* __restrict__ b2,
    float* __restrict__ newbn)
{
  const int bid = blockIdx.x;
  const int n = bid >> 6;
  const int r = bid & 63;
  const int b = r >> 5;
  const int pix = ((r & 31) << 7) + threadIdx.x;
  float a1[32];
  #pragma unroll
  for (int j=0;j<32;j++) a1[j]=0.f;
  // node features: 40 bf16 = 5 x uint4 loads
  {
    const unsigned short* nb = nodesn + (((size_t)(b)<<HWSH) + pix)*240 + n*40;
    float xv[40];
    #pragma unroll
    for (int q5=0;q5<5;q5++){
      uint4v q = *(const uint4v*)(nb + q5*8);
      #pragma unroll
      for (int u=0;u<4;u++){ xv[q5*8+2*u] = bf16lo(q[u]); xv[q5*8+2*u+1] = bf16hi(q[u]); }
    }
    #pragma unroll 4
    for (int c=0;c<40;c++){
      const float* wr = uw1t + (n*80 + c)*32;
      float x = xv[c];
      #pragma unroll
      for (int j=0;j<32;j++) a1[j]=fmaf(x,wr[j],a1[j]);
    }
  }
  const float* mb = msgs + (((size_t)(n*2+b)<<HWSH) + pix)*40;
  #pragma unroll 2
  for (int c4=0;c4<10;c4++){
    float xv[4];
    *(float4*)xv = *(const float4*)(mb + c4*4);
    #pragma unroll
    for (int ee=0;ee<4;ee++){
      const float* wr = uw1t + (n*80+40 + c4*4+ee)*32;
      #pragma unroll
      for (int j=0;j<32;j++) a1[j]=fmaf(xv[ee],wr[j],a1[j]);
    }
  }
  #pragma unroll
  for (int j=0;j<32;j++) a1[j] = relu_(g1[n*32+j]*a1[j]+b1[n*32+j]);
  float a2[40];
  #pragma unroll
  for (int j=0;j<40;j++) a2[j]=0.f;
  for (int c=0;c<32;c++){
    const float* wr = uw2t + (n*32+c)*40;
    #pragma unroll
    for (int j=0;j<40;j++) a2[j]=fmaf(a1[c],wr[j],a2[j]);
  }
  #pragma unroll
  for (int j=0;j<40;j++)
    newbn[(((size_t)(b*240+n*40+j))<<HWSH)+pix] = relu_(g2[n*40+j]*a2[j]+b2[n*40+j]);
}

// ======== k_post: xp_infer concat (4288 blocks) + pg classifier (224) ====
__global__ __launch_bounds__(256) void k_post(
    const float* __restrict__ xp, const float* __restrict__ bg,
    const float* __restrict__ newbn, const float* __restrict__ nodes,
    const float* __restrict__ cw, const float* __restrict__ cb,
    const float* __restrict__ cnw, const float* __restrict__ cnb,
    float* __restrict__ out)
{
  if (blockIdx.x < 4288){
    int i4 = blockIdx.x*256+threadIdx.x;   // exactly 1097728
    int idx = i4 << 2;
    int b = idx / (536*4096);
    int r = idx - b*(536*4096);
    int ch = r >> HWSH;
    int off = r & 4095;
    float4 v;
    if (ch < 256)      v = *(const float4*)&xp[(((size_t)(b*256+ch))<<HWSH)+off];
    else if (ch < 296) v = *(const float4*)&bg[(((size_t)(b*40+ch-256))<<HWSH)+off];
    else               v = *(const float4*)&newbn[(((size_t)(b*240+ch-296))<<HWSH)+off];
    *(float4*)&out[idx] = v;
  } else {
    int idx = (blockIdx.x-4288)*256+threadIdx.x;   // exactly 57344
    int b = idx / (7*4096);
    int r = idx - b*7*4096;
    int g = r >> HWSH;
    int off = r & 4095;
    float a = cb[g] + cnb[g];
    if (g == 0){
      for (int c=0;c<40;c++){
        float v = bg[(((size_t)(b*40+c))<<HWSH)+off];
        a = fmaf(v, cw[c]+cnw[c], a);
      }
    } else {
      for (int c=0;c<40;c++){
        float vo = nodes[(((size_t)(b*240+(g-1)*40+c))<<HWSH)+off];
        float vn = newbn[(((size_t)(b*240+(g-1)*40+c))<<HWSH)+off];
        a = fmaf(vo, cw[g*40+c], a);
        a = fmaf(vn, cnw[g*40+c], a);
      }
    }
    out[4390912 + idx] = a;
  }
}

extern "C" void kernel_launch(void* const* d_in, const int* in_sizes, int n_in,
                              void* d_out, int out_size, void* d_ws, size_t ws_size,
                              hipStream_t stream)
{
  const float* xp       = (const float*)d_in[0];
  const float* xh       = (const float*)d_in[1];
  const float* xf       = (const float*)d_in[2];
  const float* p_w      = (const float*)d_in[3];
  const float* p_g      = (const float*)d_in[4];
  const float* p_b      = (const float*)d_in[5];
  const float* bg_w     = (const float*)d_in[6];
  const float* bg_g     = (const float*)d_in[7];
  const float* bg_b     = (const float*)d_in[8];
  const float* e_off1_w = (const float*)d_in[9];
  const float* e_off1_b = (const float*)d_in[10];
  const float* e_dcn1_w = (const float*)d_in[11];
  const float* e_bn1_g  = (const float*)d_in[12];
  const float* e_bn1_b  = (const float*)d_in[13];
  const float* e_off2_w = (const float*)d_in[14];
  const float* e_off2_b = (const float*)d_in[15];
  const float* e_dcn2_w = (const float*)d_in[16];
  const float* e_bn2_g  = (const float*)d_in[17];
  const float* e_bn2_b  = (const float*)d_in[18];
  const float* e_att_w  = (const float*)d_in[19];
  const float* e_att_b  = (const float*)d_in[20];
  const float* u_w1     = (const float*)d_in[21];
  const float* u_g1     = (const float*)d_in[22];
  const float* u_b1     = (const float*)d_in[23];
  const float* u_w2     = (const float*)d_in[24];
  const float* u_g2     = (const float*)d_in[25];
  const float* u_b2     = (const float*)d_in[26];
  const float* cls_w    = (const float*)d_in[27];
  const float* cls_b    = (const float*)d_in[28];
  const float* cls_nw   = (const float*)d_in[29];
  const float* cls_nb   = (const float*)d_in[30];

  float* ws     = (float*)d_ws;
  float* nodes  = ws + NODES_OFF;
  unsigned short* nodesn = (unsigned short*)(ws + NODESN_OFF);
  float* bgb    = ws + BG_OFF;
  float* h1     = ws + H1_OFF;
  unsigned short* h1n = (unsigned short*)(ws + H1N_OFF);
  float* om     = ws + OM_OFF;
  float* msgs   = ws + MSGS_OFF;
  float* newbn  = ws + NEWBN_OFF;
  float* wo1t   = ws + WO1T_OFF;
  float* wo2t   = ws + WO2T_OFF;
  float* pwt    = ws + PWT_OFF;
  float* bgwt   = ws + BGWT_OFF;
  float* uw1t   = ws + UW1T_OFF;
  float* uw2t   = ws + UW2T_OFF;
  const unsigned short* bs1u = (const unsigned short*)(ws + BS1_OFF);
  const unsigned short* bs2u = (const unsigned short*)(ws + BS2_OFF);

  hipMemsetAsync(msgs, 0, (size_t)1966080*sizeof(float), stream);
  k_pre<<<2566, 256, 0, stream>>>(e_off1_w, e_off2_w, p_w, bg_w, u_w1, u_w2,
                                  e_dcn1_w, e_dcn2_w, ws);
  k_gemm1<<<1792, 64, 0, stream>>>(xp, xh, xf, pwt, p_g, p_b, bgwt, bg_g, bg_b,
                                   nodes, nodesn, bgb);
  k_off<1><<<1280, 256, 0, stream>>>(nodes, nullptr, wo1t, e_off1_b, om);
  k_dcn<1><<<5120, 64, 0, stream>>>(nodesn, nullptr, om, bs1u, e_bn1_g, e_bn1_b,
                                    nullptr, nullptr, h1, h1n);
  k_off<2><<<1280, 256, 0, stream>>>(nullptr, h1, wo2t, e_off2_b, om);
  k_dcn<2><<<5120, 64, 0, stream>>>(nodesn, h1n, om, bs2u, e_bn2_g, e_bn2_b,
                                    e_att_w, e_att_b, msgs, nullptr);
  k_upd<<<384, 128, 0, stream>>>(nodesn, msgs, uw1t, u_g1, u_b1, uw2t, u_g2, u_b2, newbn);
  k_post<<<4512, 256, 0, stream>>>(xp, bgb, newbn, nodes, cls_w, cls_b, cls_nw, cls_nb,
                                   (float*)d_out);
}

// Round 20
// 299.325 us; speedup vs baseline: 1.5521x; 1.5065x over previous
//
#include <hip/hip_runtime.h>
#include <math.h>

// Decoder_9887014716020 — R19: k_off -> MFMA conv (bf16 NHWC inputs, static
// tap shifts; 27 loads + 54 MFMA/wave vs 480 shfl + 6000 VALU). h1 fp32 store
// dropped (dead). Rest identical to R16/R19 best build.
// B=2, H=W=64 (HW=4096), HD=40, N_NODES=6, 10 edges.

#define HWSH 12      // 4096 = 1<<12

__device__ __constant__ int c_src[10] = {0,1,1,1,2,2,3,4,4,5};
__device__ __constant__ int c_dst[10] = {1,0,2,4,1,3,2,1,5,4};

typedef __attribute__((ext_vector_type(8))) short short8;
typedef __attribute__((ext_vector_type(4))) float f32x4;
typedef __attribute__((ext_vector_type(4))) unsigned int uint4v;

// ---- workspace layout (float offsets; bf16 regions noted) ----
constexpr size_t NODES_OFF  = 0;          // NCHW 2*240*4096 fp32 (k_post)
constexpr size_t NODESN_OFF = 1966080;    // NHWC [b][4096][240] BF16
constexpr size_t BG_OFF     = 3932160;    // 2*40*4096
constexpr size_t H1N_OFF    = 10813440;   // NHWC [20][4096][80] BF16
constexpr size_t OM_OFF     = 17367040;   // 10*2*27*4096 fp32
constexpr size_t MSGS_OFF   = 19578880;   // NHWC [6*2][4096][40] fp32
constexpr size_t NEWBN_OFF  = 21544960;   // NCHW 2*240*4096
constexpr size_t BS1_OFF    = 23511040;   // dcn B-frags s1: 691200 ushort
constexpr size_t BS2_OFF    = 23856640;   // s2: 414720 ushort
constexpr size_t BO1_OFF    = 24064000;   // off1 B-frags: 276480 ushort (138240 fl)
constexpr size_t BO2_OFF    = 24202240;   // off2 B-frags: 276480 ushort
constexpr size_t PWT_OFF    = 24340480;   // 256*240
constexpr size_t BGWT_OFF   = 24401920;   // 768*40
constexpr size_t UW1T_OFF   = 24432640;   // 6*80*32
constexpr size_t UW2T_OFF   = 24448000;   // 6*32*40 -> end 24,455,680 (97.8MB)

__device__ inline float relu_(float x){ return x > 0.f ? x : 0.f; }
__device__ inline float sigm_(float x){ return 1.f/(1.f + __expf(-x)); }
__device__ inline unsigned short bf16rne(float x){
  unsigned int u = __float_as_uint(x);
  unsigned int r = (u + 0x7fffu + ((u>>16)&1u)) >> 16;
  return (unsigned short)r;
}
__device__ inline float bf16f(unsigned short h){
  return __uint_as_float(((unsigned int)h)<<16);
}
__device__ inline float bf16lo(unsigned int u){ return __uint_as_float(u<<16); }
__device__ inline float bf16hi(unsigned int u){ return __uint_as_float(u & 0xffff0000u); }

// ======== k_pre: transposes + B-fragment prepacks (1261 blocks) ============
// [0,450) small transposes | [450,585) bo1 | [585,720) bo2
// [720,1058) bs1 | [1058,1261) bs2
__global__ __launch_bounds__(256) void k_pre(
    const float* __restrict__ off1w, const float* __restrict__ off2w,
    const float* __restrict__ p_w,  const float* __restrict__ bg_w,
    const float* __restrict__ u_w1, const float* __restrict__ u_w2,
    const float* __restrict__ dcn1w, const float* __restrict__ dcn2w,
    float* __restrict__ ws)
{
  const int bid = blockIdx.x;
  const int tid = threadIdx.x;
  if (bid < 450){
    int i = bid*256 + tid;
    if (i < 61440){                        // pwt[c][o]
      int o=i%240; int c=i/240;
      ws[PWT_OFF+i] = p_w[(size_t)o*256+c];
    } else if (i < 92160){                 // bgwt[c][o]
      int j = i-61440;
      int o=j%40; int c=j/40;
      ws[BGWT_OFF+j] = bg_w[(size_t)o*768+c];
    } else if (i < 107520){                // uw1t[n][c][o]
      int j = i-92160;
      int o=j%32; int t2=j/32; int c=t2%80; int n=t2/80;
      ws[UW1T_OFF+j] = u_w1[(size_t)((n*32+o)*80)+c];
    } else if (i < 115200){                // uw2t[n][c][o]
      int j = i-107520;
      int o=j%40; int t2=j/40; int c=t2%32; int n=t2/32;
      ws[UW2T_OFF+j] = u_w2[(size_t)((n*40+o)*32)+c];
    }
  } else if (bid < 585){
    // bo1: q = ((e*9+tap)*3+kst)*2+nt; n = nt*16+l15 (27-pad-32), c = kst*32+lg*8+j
    int t = (bid-450)*256 + tid;
    if (t < 34560){
      int lane = t & 63; int q = t >> 6;
      int nt = q % 2; int q2 = q/2; int kst = q2 % 3; q2/=3; int tap = q2 % 9; int e = q2/9;
      int n  = nt*16 + (lane & 15);
      int c0 = kst*32 + ((lane>>4))*8;
      union { unsigned int u[4]; } r;
      unsigned short v[8];
      #pragma unroll
      for (int j=0;j<8;j++){
        int c = c0 + j;
        float w = (n < 27 && c < 80) ? off1w[(size_t)((e*27+n)*80+c)*9+tap] : 0.f;
        v[j] = bf16rne(w);
      }
      #pragma unroll
      for (int j=0;j<4;j++) r.u[j] = (unsigned int)v[2*j] | ((unsigned int)v[2*j+1]<<16);
      unsigned int* dst = (unsigned int*)((unsigned short*)(ws + BO1_OFF) + (size_t)t*8);
      dst[0]=r.u[0]; dst[1]=r.u[1]; dst[2]=r.u[2]; dst[3]=r.u[3];
    }
  } else if (bid < 720){
    int t = (bid-585)*256 + tid;
    if (t < 34560){
      int lane = t & 63; int q = t >> 6;
      int nt = q % 2; int q2 = q/2; int kst = q2 % 3; q2/=3; int tap = q2 % 9; int e = q2/9;
      int n  = nt*16 + (lane & 15);
      int c0 = kst*32 + ((lane>>4))*8;
      union { unsigned int u[4]; } r;
      unsigned short v[8];
      #pragma unroll
      for (int j=0;j<8;j++){
        int c = c0 + j;
        float w = (n < 27 && c < 80) ? off2w[(size_t)((e*27+n)*80+c)*9+tap] : 0.f;
        v[j] = bf16rne(w);
      }
      #pragma unroll
      for (int j=0;j<4;j++) r.u[j] = (unsigned int)v[2*j] | ((unsigned int)v[2*j+1]<<16);
      unsigned int* dst = (unsigned int*)((unsigned short*)(ws + BO2_OFF) + (size_t)t*8);
      dst[0]=r.u[0]; dst[1]=r.u[1]; dst[2]=r.u[2]; dst[3]=r.u[3];
    }
  } else if (bid < 1058){
    // bs1: q = ((e*9+k)*3+kst)*5+nt
    int t = (bid-720)*256 + tid;
    if (t < 86400){
      int lane = t & 63; int q = t >> 6;
      int nt = q % 5; int q2 = q/5; int kst = q2 % 3; q2/=3; int k = q2 % 9; int e = q2/9;
      int n  = nt*16 + (lane & 15);
      int c0 = kst*32 + (lane>>4)*8;
      union { unsigned int u[4]; } r;
      unsigned short v[8];
      #pragma unroll
      for (int j=0;j<8;j++){
        int c = c0 + j;
        float w = (c < 80) ? dcn1w[(size_t)((e*80+n)*80+c)*9+k] : 0.f;
        v[j] = bf16rne(w);
      }
      #pragma unroll
      for (int j=0;j<4;j++) r.u[j] = (unsigned int)v[2*j] | ((unsigned int)v[2*j+1]<<16);
      unsigned int* dst = (unsigned int*)((unsigned short*)(ws + BS1_OFF) + (size_t)t*8);
      dst[0]=r.u[0]; dst[1]=r.u[1]; dst[2]=r.u[2]; dst[3]=r.u[3];
    }
  } else {
    // bs2: q = ((e*9+k)*3+kst)*3+nt
    int t = (bid-1058)*256 + tid;
    if (t < 51840){
      int lane = t & 63; int q = t >> 6;
      int nt = q % 3; int q2 = q/3; int kst = q2 % 3; q2/=3; int k = q2 % 9; int e = q2/9;
      int n  = nt*16 + (lane & 15);
      int c0 = kst*32 + (lane>>4)*8;
      union { unsigned int u[4]; } r;
      unsigned short v[8];
      #pragma unroll
      for (int j=0;j<8;j++){
        int c = c0 + j;
        float w = (n < 40 && c < 80) ? dcn2w[(size_t)((e*40+n)*80+c)*9+k] : 0.f;
        v[j] = bf16rne(w);
      }
      #pragma unroll
      for (int j=0;j<4;j++) r.u[j] = (unsigned int)v[2*j] | ((unsigned int)v[2*j+1]<<16);
      unsigned int* dst = (unsigned int*)((unsigned short*)(ws + BS2_OFF) + (size_t)t*8);
      dst[0]=r.u[0]; dst[1]=r.u[1]; dst[2]=r.u[2]; dst[3]=r.u[3];
    }
  }
}

// ======== k_gemm1 v4: ILP-8 blocked loads; NHWC mirror stored bf16 =========
__global__ __launch_bounds__(64, 4) void k_gemm1(
    const float* __restrict__ xp, const float* __restrict__ xh, const float* __restrict__ xf,
    const float* __restrict__ pwt, const float* __restrict__ pg, const float* __restrict__ pb_,
    const float* __restrict__ bgwt, const float* __restrict__ gg, const float* __restrict__ gb,
    float* __restrict__ nodes, unsigned short* __restrict__ nodesn, float* __restrict__ bg)
{
  const int lane = threadIdx.x;
  if (blockIdx.x < 1536){
    const int chunk = blockIdx.x & 31;     // 32 chunks of 256 px (2 batches)
    const int og    = blockIdx.x >> 5;     // 48 groups of 5 oc
    const int b   = chunk >> 4;
    const int px  = ((chunk & 15) << 8) + (lane << 2);
    const int o0  = og*5;
    float acc[4][5];
    #pragma unroll
    for (int p=0;p<4;p++)
      #pragma unroll
      for (int j=0;j<5;j++) acc[p][j]=0.f;
    const float* xb = xp + (((size_t)b)<<20) + px;
    #pragma unroll 1
    for (int c8=0;c8<32;c8++){
      float xv[8][4];
      #pragma unroll
      for (int j=0;j<8;j++)
        *(float4*)&xv[j][0] = *(const float4*)(xb + (((size_t)(c8*8+j))<<HWSH));
      #pragma unroll
      for (int j=0;j<8;j++){
        const float* wr = pwt + (c8*8+j)*240 + o0;
        #pragma unroll
        for (int jj=0;jj<5;jj++){
          float w = wr[jj];
          #pragma unroll
          for (int p=0;p<4;p++) acc[p][jj] = fmaf(xv[j][p], w, acc[p][jj]);
        }
      }
    }
    #pragma unroll
    for (int j=0;j<5;j++){
      int o = o0+j;
      float g = pg[o], bb = pb_[o];
      float v[4];
      #pragma unroll
      for (int p=0;p<4;p++) v[p] = relu_(g*acc[p][j]+bb);
      *(float4*)&nodes[(((size_t)(b*240+o))<<HWSH) + px] = *(float4*)v;
      #pragma unroll
      for (int p=0;p<4;p++)
        nodesn[(((size_t)(b)<<HWSH) + px + p)*240 + o] = bf16rne(v[p]);
    }
  } else {
    const int r2 = blockIdx.x - 1536;
    const int chunk = r2 & 31;
    const int og    = r2 >> 5;             // 8 groups of 5 oc
    const int b   = chunk >> 4;
    const int px  = ((chunk & 15) << 8) + (lane << 2);
    const int o0  = og*5;
    float acc[4][5];
    #pragma unroll
    for (int p=0;p<4;p++)
      #pragma unroll
      for (int j=0;j<5;j++) acc[p][j]=0.f;
    const float* srcs[3] = {xp, xh, xf};
    #pragma unroll 1
    for (int part=0;part<3;part++){
      const float* xb = srcs[part] + (((size_t)b)<<20) + px;
      const float* wp = bgwt + part*256*40 + o0;
      #pragma unroll 1
      for (int c8=0;c8<32;c8++){
        float xv[8][4];
        #pragma unroll
        for (int j=0;j<8;j++)
          *(float4*)&xv[j][0] = *(const float4*)(xb + (((size_t)(c8*8+j))<<HWSH));
        #pragma unroll
        for (int j=0;j<8;j++){
          const float* wr = wp + (c8*8+j)*40;
          #pragma unroll
          for (int jj=0;jj<5;jj++){
            float w = wr[jj];
            #pragma unroll
            for (int p=0;p<4;p++) acc[p][jj] = fmaf(xv[j][p], w, acc[p][jj]);
          }
        }
      }
    }
    #pragma unroll
    for (int j=0;j<5;j++){
      int o = o0+j;
      float g = gg[o], bb = gb[o];
      float v[4];
      #pragma unroll
      for (int p=0;p<4;p++) v[p] = relu_(g*acc[p][j]+bb);
      *(float4*)&bg[(((size_t)(b*40+o))<<HWSH) + px] = *(float4*)v;
    }
  }
}

// ======== k_off (MFMA): 3x3 conv 80->27 via per-tap shifted NHWC loads =====
// grid 5120 = e*512 + b*256 + h*4 + wv; block 64 = one wave; 16 px per wave.
// A-frag: m=px=wv*16+l15, k=(kst,lg*8+j) -> one uint4 (8 bf16 ch) at shifted
// pixel (h+ky-1, px+kx-1). B prepacked. acc init = bias. NT=2 (27 pad 32).
template<int STAGE>
__global__ __launch_bounds__(64, 4) void k_off(
    const unsigned short* __restrict__ xin,   // nodesn (s1) or h1n (s2)
    const unsigned short* __restrict__ bfr,   // bo1 or bo2 fragments
    const float* __restrict__ bo,             // bias [10][27]
    float* __restrict__ om)
{
  constexpr int CS = (STAGE==1) ? 240 : 80;
  const int bid = blockIdx.x;
  const int e  = bid >> 9;
  const int b  = (bid >> 8) & 1;
  const int h  = (bid >> 2) & 63;
  const int wv = bid & 3;
  const int lane = threadIdx.x;
  const int l15 = lane & 15;
  const int lg  = lane >> 4;
  const int px  = (wv<<4) + l15;
  const int sn = c_src[e], dn = c_dst[e];

  // per-group channel offsets + base
  const unsigned short* base;
  int cc0, cc1, cc2;
  if (STAGE==1){
    base = xin + ((size_t)(b)<<HWSH)*240;
    int t[3];
    #pragma unroll
    for (int g=0; g<3; g++){
      int cg = g*32 + lg*8;
      t[g] = (cg < 40) ? (sn*40 + cg) : (dn*40 + cg - 40);
    }
    cc0=t[0]; cc1=t[1]; cc2=t[2];
  } else {
    base = xin + ((size_t)(e*2+b)<<HWSH)*80;
    cc0 = lg*8; cc1 = 32+lg*8; cc2 = 64+lg*8;
  }

  f32x4 acc[2];
  #pragma unroll
  for (int nt=0;nt<2;nt++){
    int n = nt*16 + l15;
    float bias = (n < 27) ? bo[e*27+n] : 0.f;
    #pragma unroll
    for (int r=0;r<4;r++) acc[nt][r] = bias;
  }

  const unsigned short* bft = bfr + (size_t)e*9*3*2*512;

  #pragma unroll 1
  for (int t=0;t<9;t++){
    int ky = t/3, kx = t - 3*ky;
    int row = h + ky - 1;
    int col = px + kx - 1;
    bool rowok = ((unsigned)row < 64u);
    bool colok = ((unsigned)col < 64u);
    bool ok = rowok && colok;
    size_t po = ok ? (size_t)((row<<6)+col)*CS : 0;

    #pragma unroll
    for (int g=0; g<3; g++){
      int cc = (g==0)?cc0:(g==1)?cc1:cc2;
      const bool active = ok && ((g < 2) || (lg < 2));
      union { unsigned int u[4]; short8 v; } ah;
      if (active){
        uint4v q = *(const uint4v*)(base + po + cc);
        ah.u[0]=q[0]; ah.u[1]=q[1]; ah.u[2]=q[2]; ah.u[3]=q[3];
      } else {
        ah.u[0]=ah.u[1]=ah.u[2]=ah.u[3]=0u;
      }
      #pragma unroll
      for (int nt=0;nt<2;nt++){
        union { unsigned int u[4]; short8 v; } bf;
        const unsigned int* pb2 = (const unsigned int*)
          (bft + ((size_t)(((t*3 + g)*2 + nt)*64 + lane))*8);
        bf.u[0]=pb2[0]; bf.u[1]=pb2[1]; bf.u[2]=pb2[2]; bf.u[3]=pb2[3];
        acc[nt] = __builtin_amdgcn_mfma_f32_16x16x32_bf16(ah.v, bf.v, acc[nt], 0,0,0);
      }
    }
  }

  // epilogue: D col n = nt*16+l15 (oc), row -> pixel = wv*16 + lg*4 + r
  #pragma unroll
  for (int nt=0;nt<2;nt++){
    int n = nt*16 + l15;
    if (n < 27){
      #pragma unroll
      for (int r=0;r<4;r++){
        int pxs = (wv<<4) + lg*4 + r;
        om[(((size_t)((e*2+b)*27 + n))<<HWSH) + (h<<6) + pxs] = acc[nt][r];
      }
    }
  }
}

// ======== k_dcn: 1-wave blocks, bf16-NHWC uint4 gather + MFMA conv =========
// grid 5120 = e*512 + b*256 + h*4 + wv; block 64 = one wave.
template<int STAGE>
__global__ __launch_bounds__(64, 4) void k_dcn(
    const unsigned short* __restrict__ nodesn, const unsigned short* __restrict__ h1n,
    const float* __restrict__ om, const unsigned short* __restrict__ bs,
    const float* __restrict__ bng, const float* __restrict__ bnb,
    const float* __restrict__ attw, const float* __restrict__ attb,
    float* __restrict__ outp, unsigned short* __restrict__ outp2)
{
  constexpr int NT = (STAGE==1) ? 5 : 3;
  constexpr int CS = (STAGE==1) ? 240 : 80;     // NHWC channel stride (ushorts)
  const int bid = blockIdx.x;
  const int e  = bid >> 9;
  const int b  = (bid >> 8) & 1;
  const int h  = (bid >> 2) & 63;
  const int wv = bid & 3;
  const int lane = threadIdx.x;
  const int l15 = lane & 15;
  const int lg  = lane >> 4;
  const int px  = (wv<<4) + l15;
  const int off_px = (h<<6) + px;
  const int sn = c_src[e], dn = c_dst[e];

  const float* ombase = om + (((size_t)((e*2+b)*27))<<HWSH) + off_px;

  // per-lane group base pointers (group g = concat-ch [g*32+lg*8, +8))
  const unsigned short* gbase0; const unsigned short* gbase1; const unsigned short* gbase2;
  {
    const unsigned short* t[3];
    #pragma unroll
    for (int g=0; g<3; g++){
      int cg = g*32 + lg*8;
      if (STAGE==1){
        int cc = (cg < 40) ? (sn*40 + cg) : (dn*40 + cg - 40);
        t[g] = nodesn + ((size_t)(b)<<HWSH)*240 + cc;
      } else {
        t[g] = h1n + ((size_t)(e*2+b)<<HWSH)*80 + cg;
      }
    }
    gbase0 = t[0]; gbase1 = t[1]; gbase2 = t[2];
  }

  // stage2: per-lane attention factor for pixel px (bf16 NHWC: 5 uint4 loads)
  float attf = 0.f;
  if (STAGE==2){
    float at = attb[e];
    const unsigned short* nb = nodesn + (((size_t)(b)<<HWSH) + off_px)*240 + sn*40;
    #pragma unroll
    for (int q5=0;q5<5;q5++){
      uint4v q = *(const uint4v*)(nb + q5*8);
      #pragma unroll
      for (int u=0;u<4;u++){
        at = fmaf(bf16lo(q[u]), attw[e*40+q5*8+2*u],   at);
        at = fmaf(bf16hi(q[u]), attw[e*40+q5*8+2*u+1], at);
      }
    }
    attf = 2.f - sigm_(at);
  }

  f32x4 acc[NT];
  #pragma unroll
  for (int nt=0;nt<NT;nt++)
    #pragma unroll
    for (int r=0;r<4;r++) acc[nt][r] = 0.f;

  const unsigned short* bsk = bs + (size_t)e*9*3*NT*512;

  // om prefetch pipeline: (dy,dx,m) for tap k loaded one iteration ahead
  float dyc = ombase[0];
  float dxc = ombase[(size_t)1<<HWSH];
  float mrc = ombase[(size_t)18<<HWSH];

  #pragma unroll 1
  for (int k=0;k<9;k++){
    float dyn, dxn, mrn;
    if (k < 8){
      dyn = ombase[((size_t)(2*k+2))<<HWSH];
      dxn = ombase[((size_t)(2*k+3))<<HWSH];
      mrn = ombase[((size_t)(19+k))<<HWSH];
    }
    float mv  = sigm_(mrc);
    int ky = k/3, kx = k - 3*ky;
    float py  = dyc + (float)(ky - 1 + h);
    float pxf = dxc + (float)(kx - 1) + (float)px;
    float y0f = floorf(py), x0f = floorf(pxf);
    float wy = py - y0f, wx = pxf - x0f;
    int y0 = (int)y0f, x0i = (int)x0f;
    int y1 = y0+1, x1i = x0i+1;
    bool yv0 = (y0>=0)&&(y0<64),  yv1 = (y1>=0)&&(y1<64);
    bool xv0 = (x0i>=0)&&(x0i<64), xv1 = (x1i>=0)&&(x1i<64);
    float w00 = (yv0&&xv0) ? (1.f-wy)*(1.f-wx)*mv : 0.f;
    float w01 = (yv0&&xv1) ? (1.f-wy)*wx*mv       : 0.f;
    float w10 = (yv1&&xv0) ? wy*(1.f-wx)*mv       : 0.f;
    float w11 = (yv1&&xv1) ? wy*wx*mv             : 0.f;
    int yc0 = min(max(y0 ,0),63), yc1 = min(max(y1 ,0),63);
    int xc0 = min(max(x0i,0),63), xc1 = min(max(x1i,0),63);
    size_t a00 = (size_t)((yc0<<6)+xc0)*CS, a01 = (size_t)((yc0<<6)+xc1)*CS;
    size_t a10 = (size_t)((yc1<<6)+xc0)*CS, a11 = (size_t)((yc1<<6)+xc1)*CS;

    // ---- per group: 4 uint4 loads (4 corners x 8 bf16 ch) -> frags ----
    #pragma unroll
    for (int g=0; g<3; g++){
      const unsigned short* gb = (g==0) ? gbase0 : (g==1) ? gbase1 : gbase2;
      const bool active = (g < 2) || (lg < 2);   // K-pad 80..95 -> zero frags
      union { unsigned int u[4]; short8 v; } ah, al;
      if (active){
        uint4v q00 = *(const uint4v*)(gb + a00);
        uint4v q01 = *(const uint4v*)(gb + a01);
        uint4v q10 = *(const uint4v*)(gb + a10);
        uint4v q11 = *(const uint4v*)(gb + a11);
        #pragma unroll
        for (int u=0;u<4;u++){
          float s0 = fmaf(w00,bf16lo(q00[u]), fmaf(w01,bf16lo(q01[u]),
                       fmaf(w10,bf16lo(q10[u]), w11*bf16lo(q11[u]))));
          float s1 = fmaf(w00,bf16hi(q00[u]), fmaf(w01,bf16hi(q01[u]),
                       fmaf(w10,bf16hi(q10[u]), w11*bf16hi(q11[u]))));
          unsigned short h0 = bf16rne(s0), h1_ = bf16rne(s1);
          unsigned short l0 = bf16rne(s0 - bf16f(h0)), l1 = bf16rne(s1 - bf16f(h1_));
          ah.u[u] = (unsigned int)h0 | ((unsigned int)h1_<<16);
          al.u[u] = (unsigned int)l0 | ((unsigned int)l1<<16);
        }
      } else {
        ah.u[0]=ah.u[1]=ah.u[2]=ah.u[3]=0u;
        al.u[0]=al.u[1]=al.u[2]=al.u[3]=0u;
      }
      #pragma unroll
      for (int nt=0;nt<NT;nt++){
        union { unsigned int u[4]; short8 v; } bf;
        const unsigned int* pb2 = (const unsigned int*)
          (bsk + ((size_t)((g*NT + nt)*64 + lane))*8);
        bf.u[0]=pb2[0]; bf.u[1]=pb2[1]; bf.u[2]=pb2[2]; bf.u[3]=pb2[3];
        acc[nt] = __builtin_amdgcn_mfma_f32_16x16x32_bf16(ah.v, bf.v, acc[nt], 0,0,0);
        acc[nt] = __builtin_amdgcn_mfma_f32_16x16x32_bf16(al.v, bf.v, acc[nt], 0,0,0);
      }
    }
    bsk += 3*NT*512;
    dyc = dyn; dxc = dxn; mrc = mrn;
  }

  // ---- epilogue: D col n = nt*16+l15, row -> pixel = 16wv + lg*4 + r ----
  if (STAGE==1){
    #pragma unroll
    for (int nt=0;nt<NT;nt++){
      int n = nt*16 + l15;
      float g = bng[e*80+n], bb = bnb[e*80+n];
      #pragma unroll
      for (int r=0;r<4;r++){
        int pxs = (wv<<4) + lg*4 + r;
        float v = relu_(g*acc[nt][r] + bb);
        outp2[(((size_t)(e*2+b)<<HWSH) + (h<<6) + pxs)*80 + n] = bf16rne(v);     // NHWC bf16 only
      }
    }
  } else {
    // DIVERGENCE-SAFE: shfl with ALL lanes active, BEFORE the n<40 guard.
    float fac[4];
    #pragma unroll
    for (int r=0;r<4;r++) fac[r] = __shfl(attf, 4*lg + r, 64);
    #pragma unroll
    for (int nt=0;nt<NT;nt++){
      int n = nt*16 + l15;
      if (n < 40){
        float g = bng[e*40+n], bb = bnb[e*40+n];
        #pragma unroll
        for (int r=0;r<4;r++){
          int pxs = (wv<<4) + lg*4 + r;
          float v = relu_(g*acc[nt][r] + bb) * fac[r];
          atomicAdd(&outp[(((size_t)(dn*2+b)<<HWSH) + (h<<6) + pxs)*40 + n], v);  // fp32 msgs
        }
      }
    }
  }
}

// ---- node update: 2-layer 1x1 MLP; nodesn bf16, msgs fp32 -> newbn NCHW ----
__global__ __launch_bounds__(128) void k_upd(
    const unsigned short* __restrict__ nodesn, const float* __restrict__ msgs,
    const float* __restrict__ uw1t, const float* __restrict__ g1, const float* __restrict__ b1,
    const float* __restrict__ uw2t, const float* __restrict__ g2, const float* __restrict__ b2,
    float* __restrict__ newbn)
{
  const int bid = blockIdx.x;
  const int n = bid >> 6;
  const int r = bid & 63;
  const int b = r >> 5;
  const int pix = ((r & 31) << 7) + threadIdx.x;
  float a1[32];
  #pragma unroll
  for (int j=0;j<32;j++) a1[j]=0.f;
  // node features: 40 bf16 = 5 x uint4 loads
  {
    const unsigned short* nb = nodesn + (((size_t)(b)<<HWSH) + pix)*240 + n*40;
    float xv[40];
    #pragma unroll
    for (int q5=0;q5<5;q5++){
      uint4v q = *(const uint4v*)(nb + q5*8);
      #pragma unroll
      for (int u=0;u<4;u++){ xv[q5*8+2*u] = bf16lo(q[u]); xv[q5*8+2*u+1] = bf16hi(q[u]); }
    }
    #pragma unroll 4
    for (int c=0;c<40;c++){
      const float* wr = uw1t + (n*80 + c)*32;
      float x = xv[c];
      #pragma unroll
      for (int j=0;j<32;j++) a1[j]=fmaf(x,wr[j],a1[j]);
    }
  }
  const float* mb = msgs + (((size_t)(n*2+b)<<HWSH) + pix)*40;
  #pragma unroll 2
  for (int c4=0;c4<10;c4++){
    float xv[4];
    *(float4*)xv = *(const float4*)(mb + c4*4);
    #pragma unroll
    for (int ee=0;ee<4;ee++){
      const float* wr = uw1t + (n*80+40 + c4*4+ee)*32;
      #pragma unroll
      for (int j=0;j<32;j++) a1[j]=fmaf(xv[ee],wr[j],a1[j]);
    }
  }
  #pragma unroll
  for (int j=0;j<32;j++) a1[j] = relu_(g1[n*32+j]*a1[j]+b1[n*32+j]);
  float a2[40];
  #pragma unroll
  for (int j=0;j<40;j++) a2[j]=0.f;
  for (int c=0;c<32;c++){
    const float* wr = uw2t + (n*32+c)*40;
    #pragma unroll
    for (int j=0;j<40;j++) a2[j]=fmaf(a1[c],wr[j],a2[j]);
  }
  #pragma unroll
  for (int j=0;j<40;j++)
    newbn[(((size_t)(b*240+n*40+j))<<HWSH)+pix] = relu_(g2[n*40+j]*a2[j]+b2[n*40+j]);
}

// ======== k_post: xp_infer concat (4288 blocks) + pg classifier (224) ====
__global__ __launch_bounds__(256) void k_post(
    const float* __restrict__ xp, const float* __restrict__ bg,
    const float* __restrict__ newbn, const float* __restrict__ nodes,
    const float* __restrict__ cw, const float* __restrict__ cb,
    const float* __restrict__ cnw, const float* __restrict__ cnb,
    float* __restrict__ out)
{
  if (blockIdx.x < 4288){
    int i4 = blockIdx.x*256+threadIdx.x;   // exactly 1097728
    int idx = i4 << 2;
    int b = idx / (536*4096);
    int r = idx - b*(536*4096);
    int ch = r >> HWSH;
    int off = r & 4095;
    float4 v;
    if (ch < 256)      v = *(const float4*)&xp[(((size_t)(b*256+ch))<<HWSH)+off];
    else if (ch < 296) v = *(const float4*)&bg[(((size_t)(b*40+ch-256))<<HWSH)+off];
    else               v = *(const float4*)&newbn[(((size_t)(b*240+ch-296))<<HWSH)+off];
    *(float4*)&out[idx] = v;
  } else {
    int idx = (blockIdx.x-4288)*256+threadIdx.x;   // exactly 57344
    int b = idx / (7*4096);
    int r = idx - b*7*4096;
    int g = r >> HWSH;
    int off = r & 4095;
    float a = cb[g] + cnb[g];
    if (g == 0){
      for (int c=0;c<40;c++){
        float v = bg[(((size_t)(b*40+c))<<HWSH)+off];
        a = fmaf(v, cw[c]+cnw[c], a);
      }
    } else {
      for (int c=0;c<40;c++){
        float vo = nodes[(((size_t)(b*240+(g-1)*40+c))<<HWSH)+off];
        float vn = newbn[(((size_t)(b*240+(g-1)*40+c))<<HWSH)+off];
        a = fmaf(vo, cw[g*40+c], a);
        a = fmaf(vn, cnw[g*40+c], a);
      }
    }
    out[4390912 + idx] = a;
  }
}

extern "C" void kernel_launch(void* const* d_in, const int* in_sizes, int n_in,
                              void* d_out, int out_size, void* d_ws, size_t ws_size,
                              hipStream_t stream)
{
  const float* xp       = (const float*)d_in[0];
  const float* xh       = (const float*)d_in[1];
  const float* xf       = (const float*)d_in[2];
  const float* p_w      = (const float*)d_in[3];
  const float* p_g      = (const float*)d_in[4];
  const float* p_b      = (const float*)d_in[5];
  const float* bg_w     = (const float*)d_in[6];
  const float* bg_g     = (const float*)d_in[7];
  const float* bg_b     = (const float*)d_in[8];
  const float* e_off1_w = (const float*)d_in[9];
  const float* e_off1_b = (const float*)d_in[10];
  const float* e_dcn1_w = (const float*)d_in[11];
  const float* e_bn1_g  = (const float*)d_in[12];
  const float* e_bn1_b  = (const float*)d_in[13];
  const float* e_off2_w = (const float*)d_in[14];
  const float* e_off2_b = (const float*)d_in[15];
  const float* e_dcn2_w = (const float*)d_in[16];
  const float* e_bn2_g  = (const float*)d_in[17];
  const float* e_bn2_b  = (const float*)d_in[18];
  const float* e_att_w  = (const float*)d_in[19];
  const float* e_att_b  = (const float*)d_in[20];
  const float* u_w1     = (const float*)d_in[21];
  const float* u_g1     = (const float*)d_in[22];
  const float* u_b1     = (const float*)d_in[23];
  const float* u_w2     = (const float*)d_in[24];
  const float* u_g2     = (const float*)d_in[25];
  const float* u_b2     = (const float*)d_in[26];
  const float* cls_w    = (const float*)d_in[27];
  const float* cls_b    = (const float*)d_in[28];
  const float* cls_nw   = (const float*)d_in[29];
  const float* cls_nb   = (const float*)d_in[30];

  float* ws     = (float*)d_ws;
  float* nodes  = ws + NODES_OFF;
  unsigned short* nodesn = (unsigned short*)(ws + NODESN_OFF);
  float* bgb    = ws + BG_OFF;
  unsigned short* h1n = (unsigned short*)(ws + H1N_OFF);
  float* om     = ws + OM_OFF;
  float* msgs   = ws + MSGS_OFF;
  float* newbn  = ws + NEWBN_OFF;
  float* pwt    = ws + PWT_OFF;
  float* bgwt   = ws + BGWT_OFF;
  float* uw1t   = ws + UW1T_OFF;
  float* uw2t   = ws + UW2T_OFF;
  const unsigned short* bs1u = (const unsigned short*)(ws + BS1_OFF);
  const unsigned short* bs2u = (const unsigned short*)(ws + BS2_OFF);
  const unsigned short* bo1u = (const unsigned short*)(ws + BO1_OFF);
  const unsigned short* bo2u = (const unsigned short*)(ws + BO2_OFF);

  hipMemsetAsync(msgs, 0, (size_t)1966080*sizeof(float), stream);
  k_pre<<<1261, 256, 0, stream>>>(e_off1_w, e_off2_w, p_w, bg_w, u_w1, u_w2,
                                  e_dcn1_w, e_dcn2_w, ws);
  k_gemm1<<<1792, 64, 0, stream>>>(xp, xh, xf, pwt, p_g, p_b, bgwt, bg_g, bg_b,
                                   nodes, nodesn, bgb);
  k_off<1><<<5120, 64, 0, stream>>>(nodesn, bo1u, e_off1_b, om);
  k_dcn<1><<<5120, 64, 0, stream>>>(nodesn, nullptr, om, bs1u, e_bn1_g, e_bn1_b,
                                    nullptr, nullptr, nullptr, h1n);
  k_off<2><<<5120, 64, 0, stream>>>(h1n, bo2u, e_off2_b, om);
  k_dcn<2><<<5120, 64, 0, stream>>>(nodesn, h1n, om, bs2u, e_bn2_g, e_bn2_b,
                                    e_att_w, e_att_b, msgs, nullptr);
  k_upd<<<384, 128, 0, stream>>>(nodesn, msgs, uw1t, u_g1, u_b1, uw2t, u_g2, u_b2, newbn);
  k_post<<<4512, 256, 0, stream>>>(xp, bgb, newbn, nodes, cls_w, cls_b, cls_nw, cls_nb,
                                   (float*)d_out);
}